// Round 1
// baseline (1109.208 us; speedup 1.0000x reference)
//
#include <hip/hip_runtime.h>
#include <cstdint>
#include <cstddef>

// Problem constants (from reference): N=100000, E=3200000, DIN=128, DHID=128, DOUT=64
// Derived dynamically from in_sizes where cheap; feature dims hardcoded.

#define LEAKY_SLOPE 0.2f

// ---------------------------------------------------------------- CSR build
__global__ void k_hist(const int* __restrict__ dst, int* __restrict__ deg,
                       int E, int N) {
  int idx = blockIdx.x * blockDim.x + threadIdx.x;
  if (idx >= E + N) return;
  int d = (idx < E) ? dst[idx] : (idx - E);   // implicit self-loop edges at tail
  atomicAdd(&deg[d], 1);
}

__global__ void k_blocksum(const int* __restrict__ deg, int* __restrict__ bsum,
                           int N) {
  __shared__ int sm[256];
  int b = blockIdx.x, t = threadIdx.x;
  int base = b * 1024 + t * 4;
  int s = 0;
#pragma unroll
  for (int j = 0; j < 4; ++j) {
    int i = base + j;
    if (i < N) s += deg[i];
  }
  sm[t] = s;
  __syncthreads();
  for (int o = 128; o; o >>= 1) {
    if (t < o) sm[t] += sm[t + o];
    __syncthreads();
  }
  if (t == 0) bsum[b] = sm[0];
}

__global__ void k_scanmid(const int* __restrict__ bsum, int* __restrict__ bpre,
                          int G, int total, int* __restrict__ off_last) {
  __shared__ int sm[256];
  int t = threadIdx.x;
  int v = (t < G) ? bsum[t] : 0;
  sm[t] = v;
  __syncthreads();
  for (int o = 1; o < 256; o <<= 1) {
    int x = (t >= o) ? sm[t - o] : 0;
    __syncthreads();
    sm[t] += x;
    __syncthreads();
  }
  if (t < G) bpre[t] = sm[t] - v;   // exclusive prefix of block sums
  if (t == 0) *off_last = total;    // off[N] = E + N
}

__global__ void k_scanfinal(const int* __restrict__ deg, const int* __restrict__ bpre,
                            int* __restrict__ off, int* __restrict__ cursor, int N) {
  __shared__ int sm[256];
  int b = blockIdx.x, t = threadIdx.x;
  int base = b * 1024 + t * 4;
  int v[4];
  int s = 0;
#pragma unroll
  for (int j = 0; j < 4; ++j) {
    int i = base + j;
    v[j] = (i < N) ? deg[i] : 0;
    s += v[j];
  }
  sm[t] = s;
  __syncthreads();
  for (int o = 1; o < 256; o <<= 1) {
    int x = (t >= o) ? sm[t - o] : 0;
    __syncthreads();
    sm[t] += x;
    __syncthreads();
  }
  int run = bpre[b] + (sm[t] - s);  // exclusive prefix for this thread's chunk
#pragma unroll
  for (int j = 0; j < 4; ++j) {
    int i = base + j;
    if (i < N) {
      off[i] = run;
      cursor[i] = run;
      run += v[j];
    }
  }
}

__global__ void k_scatter(const int* __restrict__ src, const int* __restrict__ dst,
                          int* __restrict__ cursor, int* __restrict__ csr,
                          int E, int N) {
  int idx = blockIdx.x * blockDim.x + threadIdx.x;
  if (idx >= E + N) return;
  int s, d;
  if (idx < E) { s = src[idx]; d = dst[idx]; }
  else         { s = d = idx - E; }            // self-loop
  int pos = atomicAdd(&cursor[d], 1);
  csr[pos] = s;
}

// ---------------------------------------------------------------- GEMM (f32)
// C[N][COLS] = A[N][128] @ B[128][COLS].  64-row x COLS-col tile per block,
// 256 threads (16x16), micro-tile 4 rows x (COLS/16) cols per thread.
template <int COLS>
__global__ __launch_bounds__(256) void k_gemm(const float* __restrict__ A,
                                              const float* __restrict__ Bm,
                                              float* __restrict__ C, int N) {
  constexpr int K = 128, KC = 64;
  constexpr int TN = COLS / 16;
  __shared__ float As[KC][64 + 1];   // transposed A chunk: As[k][r]; +1 pad kills write conflicts
  __shared__ float Bs[KC][COLS];
  const int t = threadIdx.x;
  const int tx = t & 15, ty = t >> 4;
  const int row0 = blockIdx.x * 64;
  float acc[4][TN] = {};

  for (int k0 = 0; k0 < K; k0 += KC) {
    // stage A chunk (64 rows x KC k), transposed into LDS
#pragma unroll
    for (int i = 0; i < 4; ++i) {
      int idx = t + 256 * i;
      int r = idx >> 4;       // 0..63
      int kq = idx & 15;      // 0..15 (x4 k's)
      int grow = row0 + r;
      float4 v = make_float4(0.f, 0.f, 0.f, 0.f);
      if (grow < N)
        v = *reinterpret_cast<const float4*>(A + (size_t)grow * K + k0 + kq * 4);
      As[kq * 4 + 0][r] = v.x;
      As[kq * 4 + 1][r] = v.y;
      As[kq * 4 + 2][r] = v.z;
      As[kq * 4 + 3][r] = v.w;
    }
    // stage B chunk (KC x COLS), row-major copy
    constexpr int BI = (KC * COLS / 4) / 256;
#pragma unroll
    for (int i = 0; i < BI; ++i) {
      int idx = t + 256 * i;
      int r = idx / (COLS / 4);
      int cq = idx % (COLS / 4);
      *reinterpret_cast<float4*>(&Bs[r][cq * 4]) =
          *reinterpret_cast<const float4*>(Bm + (size_t)(k0 + r) * COLS + cq * 4);
    }
    __syncthreads();
#pragma unroll 8
    for (int k = 0; k < KC; ++k) {
      float a[4], b[TN];
#pragma unroll
      for (int i = 0; i < 4; ++i) a[i] = As[k][ty * 4 + i];
#pragma unroll
      for (int j = 0; j < TN; ++j) b[j] = Bs[k][tx * TN + j];
#pragma unroll
      for (int i = 0; i < 4; ++i)
#pragma unroll
        for (int j = 0; j < TN; ++j) acc[i][j] += a[i] * b[j];
    }
    __syncthreads();
  }
#pragma unroll
  for (int i = 0; i < 4; ++i) {
    int grow = row0 + ty * 4 + i;
    if (grow < N) {
#pragma unroll
      for (int j = 0; j < TN; j += 4) {
        *reinterpret_cast<float4*>(C + (size_t)grow * COLS + tx * TN + j) =
            make_float4(acc[i][j], acc[i][j + 1], acc[i][j + 2], acc[i][j + 3]);
      }
    }
  }
}

// ---------------------------------------------------------------- alpha halves
// One wave per node: alpha_src[n] = h[n].a_src ; alpha_dst[n] = h[n].a_dst
template <int F>
__global__ __launch_bounds__(256) void k_alpha(const float* __restrict__ h,
                                               const float* __restrict__ a_src,
                                               const float* __restrict__ a_dst,
                                               float* __restrict__ as_,
                                               float* __restrict__ ad_, int N) {
  int wid = (blockIdx.x * blockDim.x + threadIdx.x) >> 6;
  int lane = threadIdx.x & 63;
  if (wid >= N) return;
  float ps = 0.f, pd = 0.f;
  if constexpr (F == 128) {
    float2 v = *reinterpret_cast<const float2*>(h + (size_t)wid * 128 + 2 * lane);
    ps = v.x * a_src[2 * lane] + v.y * a_src[2 * lane + 1];
    pd = v.x * a_dst[2 * lane] + v.y * a_dst[2 * lane + 1];
  } else {
    float v = h[(size_t)wid * 64 + lane];
    ps = v * a_src[lane];
    pd = v * a_dst[lane];
  }
  for (int o = 32; o; o >>= 1) {
    ps += __shfl_xor(ps, o);
    pd += __shfl_xor(pd, o);
  }
  if (lane == 0) {
    as_[wid] = ps;
    ad_[wid] = pd;
  }
}

// ---------------------------------------------------------------- aggregation
// One wave per destination node: segment softmax over incoming edges (incl.
// self-loop) + weighted gather-sum of h[src], bias, optional ReLU.
template <int F, bool RELU>
__global__ __launch_bounds__(256) void k_agg(const int* __restrict__ off,
                                             const int* __restrict__ csr,
                                             const float* __restrict__ as_,
                                             const float* __restrict__ ad_,
                                             const float* __restrict__ h,
                                             const float* __restrict__ bias,
                                             float* __restrict__ out, int N) {
  int wid = (blockIdx.x * blockDim.x + threadIdx.x) >> 6;
  int lane = threadIdx.x & 63;
  if (wid >= N) return;
  const int d = wid;
  const int s0 = off[d], s1 = off[d + 1];
  const float adv = ad_[d];

  // pass 1: segment max of leaky_relu(as[src] + ad[d])
  float lmax = -INFINITY;
  for (int base = s0; base < s1; base += 64) {
    int i = base + lane;
    if (i < s1) {
      float e = as_[csr[i]] + adv;
      e = (e > 0.f) ? e : LEAKY_SLOPE * e;
      lmax = fmaxf(lmax, e);
    }
  }
  for (int o = 32; o; o >>= 1) lmax = fmaxf(lmax, __shfl_xor(lmax, o));

  // pass 2: segment sum of exp(e - m)
  float lsum = 0.f;
  for (int base = s0; base < s1; base += 64) {
    int i = base + lane;
    if (i < s1) {
      float e = as_[csr[i]] + adv;
      e = (e > 0.f) ? e : LEAKY_SLOPE * e;
      lsum += __expf(e - lmax);
    }
  }
  for (int o = 32; o; o >>= 1) lsum += __shfl_xor(lsum, o);
  const float inv_s = 1.f / (lsum + 1e-16f);

  // pass 3: weighted aggregate of h[src]
  float acc0 = 0.f, acc1 = 0.f;
  for (int base = s0; base < s1; base += 64) {
    int i = base + lane;
    float w = 0.f;
    int sv = 0;
    if (i < s1) {
      sv = csr[i];
      float e = as_[sv] + adv;
      e = (e > 0.f) ? e : LEAKY_SLOPE * e;
      w = __expf(e - lmax) * inv_s;
    }
    const int jn = min(64, s1 - base);
    for (int j = 0; j < jn; ++j) {
      float wj = __int_as_float(__builtin_amdgcn_readlane(__float_as_int(w), j));
      int sj = __builtin_amdgcn_readlane(sv, j);
      if constexpr (F == 128) {
        float2 v = *reinterpret_cast<const float2*>(h + (size_t)sj * 128 + 2 * lane);
        acc0 += wj * v.x;
        acc1 += wj * v.y;
      } else {
        acc0 += wj * h[(size_t)sj * 64 + lane];
      }
    }
  }

  if constexpr (F == 128) {
    float o0 = acc0 + bias[2 * lane];
    float o1 = acc1 + bias[2 * lane + 1];
    if (RELU) {
      o0 = fmaxf(o0, 0.f);
      o1 = fmaxf(o1, 0.f);
    }
    *reinterpret_cast<float2*>(out + (size_t)d * 128 + 2 * lane) = make_float2(o0, o1);
  } else {
    float o0 = acc0 + bias[lane];
    if (RELU) o0 = fmaxf(o0, 0.f);
    out[(size_t)d * 64 + lane] = o0;
  }
}

// ---------------------------------------------------------------- final mean
__global__ __launch_bounds__(256) void k_mean(const float* __restrict__ out2,
                                              float* __restrict__ d_out, int N) {
  int c = threadIdx.x & 63;
  int w = threadIdx.x >> 6;                 // 0..3
  float acc = 0.f;
  for (int r = blockIdx.x * 4 + w; r < N; r += gridDim.x * 4)
    acc += out2[(size_t)r * 64 + c];
  atomicAdd(&d_out[c], acc * (1.0f / (float)N));
}

// ---------------------------------------------------------------- launch
extern "C" void kernel_launch(void* const* d_in, const int* in_sizes, int n_in,
                              void* d_out, int out_size, void* d_ws, size_t ws_size,
                              hipStream_t stream) {
  (void)n_in; (void)out_size; (void)ws_size;
  const float* x      = (const float*)d_in[0];
  const int*   edges  = (const int*)d_in[1];
  const float* W1     = (const float*)d_in[2];
  const float* a1_src = (const float*)d_in[3];
  const float* a1_dst = (const float*)d_in[4];
  const float* b1     = (const float*)d_in[5];
  const float* W2     = (const float*)d_in[6];
  const float* a2_src = (const float*)d_in[7];
  const float* a2_dst = (const float*)d_in[8];
  const float* b2     = (const float*)d_in[9];
  float* out = (float*)d_out;

  const int N = in_sizes[0] / 128;     // 100000
  const int E = in_sizes[1] / 2;       // 3200000
  const int ET = E + N;                // edges incl. self-loops
  const int G = (N + 1023) / 1024;     // scan blocks

  const int* e_src = edges;
  const int* e_dst = edges + E;

  // workspace carve-up (512B aligned slots)
  char* ws = (char*)d_ws;
  size_t o = 0;
  auto alloc = [&](size_t bytes) {
    size_t p = o;
    o += (bytes + 511) & ~(size_t)511;
    return p;
  };
  float* h1     = (float*)(ws + alloc((size_t)N * 128 * 4));
  float* g1     = (float*)(ws + alloc((size_t)N * 128 * 4));
  float* h2     = (float*)(ws + alloc((size_t)N * 64 * 4));
  float* as1    = (float*)(ws + alloc((size_t)N * 4));
  float* ad1    = (float*)(ws + alloc((size_t)N * 4));
  float* as2    = (float*)(ws + alloc((size_t)N * 4));
  float* ad2    = (float*)(ws + alloc((size_t)N * 4));
  int*   off    = (int*)(ws + alloc((size_t)(N + 1) * 4));
  int*   cursor = (int*)(ws + alloc((size_t)N * 4));
  int*   bsum   = (int*)(ws + alloc((size_t)G * 4));
  int*   bpre   = (int*)(ws + alloc((size_t)G * 4));
  int*   csr    = (int*)(ws + alloc((size_t)ET * 4));
  int*   deg    = cursor;               // deg reuses cursor slot? NO — needed simultaneously.
  // deg must coexist with cursor (scanfinal reads deg, writes cursor). Give it its own slot:
  deg = (int*)(ws + alloc((size_t)N * 4));
  float* out2 = h1;                     // h1 dead after layer-1 aggregation

  // --- CSR build (shared by both layers) ---
  hipMemsetAsync(deg, 0, (size_t)N * 4, stream);
  {
    int blocks = (ET + 255) / 256;
    k_hist<<<blocks, 256, 0, stream>>>(e_dst, deg, E, N);
  }
  k_blocksum<<<G, 256, 0, stream>>>(deg, bsum, N);
  k_scanmid<<<1, 256, 0, stream>>>(bsum, bpre, G, ET, off + N);
  k_scanfinal<<<G, 256, 0, stream>>>(deg, bpre, off, cursor, N);
  {
    int blocks = (ET + 255) / 256;
    k_scatter<<<blocks, 256, 0, stream>>>(e_src, e_dst, cursor, csr, E, N);
  }

  const int gemm_grid = (N + 63) / 64;
  const int node_wave_grid = (N + 3) / 4;   // 4 waves per 256-thread block

  // --- layer 1 ---
  k_gemm<128><<<gemm_grid, 256, 0, stream>>>(x, W1, h1, N);
  k_alpha<128><<<node_wave_grid, 256, 0, stream>>>(h1, a1_src, a1_dst, as1, ad1, N);
  k_agg<128, true><<<node_wave_grid, 256, 0, stream>>>(off, csr, as1, ad1, h1, b1, g1, N);

  // --- layer 2 ---
  k_gemm<64><<<gemm_grid, 256, 0, stream>>>(g1, W2, h2, N);
  k_alpha<64><<<node_wave_grid, 256, 0, stream>>>(h2, a2_src, a2_dst, as2, ad2, N);
  k_agg<64, false><<<node_wave_grid, 256, 0, stream>>>(off, csr, as2, ad2, h2, b2, out2, N);

  // --- mean over nodes ---
  hipMemsetAsync(out, 0, 64 * sizeof(float), stream);
  k_mean<<<256, 256, 0, stream>>>(out2, out, N);
}

// Round 2
// 1010.632 us; speedup vs baseline: 1.0975x; 1.0975x over previous
//
#include <hip/hip_runtime.h>
#include <cstdint>
#include <cstddef>

#define LEAKY_SLOPE 0.2f

typedef __attribute__((ext_vector_type(8))) short short8;   // 8 x bf16 frag
typedef __attribute__((ext_vector_type(4))) float f32x4;

// ---- bf16 helpers (manual, no header dependency; RNE; inputs are finite) ----
static __device__ inline unsigned short f2b(float f) {
  union { float f; unsigned int u; } c; c.f = f;
  unsigned int u = c.u;
  unsigned int r = (u + 0x7fffu + ((u >> 16) & 1u)) >> 16;
  return (unsigned short)r;
}
static __device__ inline float b2f(unsigned short b) {
  union { unsigned int u; float f; } c; c.u = ((unsigned int)b) << 16;
  return c.f;
}

// ---------------------------------------------------------------- CSR build
__global__ void k_hist(const int* __restrict__ dst, int* __restrict__ deg,
                       int E, int N) {
  int idx = blockIdx.x * blockDim.x + threadIdx.x;
  if (idx >= E + N) return;
  int d = (idx < E) ? dst[idx] : (idx - E);   // implicit self-loop edges at tail
  atomicAdd(&deg[d], 1);
}

__global__ void k_blocksum(const int* __restrict__ deg, int* __restrict__ bsum,
                           int N) {
  __shared__ int sm[256];
  int b = blockIdx.x, t = threadIdx.x;
  int base = b * 1024 + t * 4;
  int s = 0;
#pragma unroll
  for (int j = 0; j < 4; ++j) {
    int i = base + j;
    if (i < N) s += deg[i];
  }
  sm[t] = s;
  __syncthreads();
  for (int o = 128; o; o >>= 1) {
    if (t < o) sm[t] += sm[t + o];
    __syncthreads();
  }
  if (t == 0) bsum[b] = sm[0];
}

__global__ void k_scanmid(const int* __restrict__ bsum, int* __restrict__ bpre,
                          int G, int total, int* __restrict__ off_last) {
  __shared__ int sm[256];
  int t = threadIdx.x;
  int v = (t < G) ? bsum[t] : 0;
  sm[t] = v;
  __syncthreads();
  for (int o = 1; o < 256; o <<= 1) {
    int x = (t >= o) ? sm[t - o] : 0;
    __syncthreads();
    sm[t] += x;
    __syncthreads();
  }
  if (t < G) bpre[t] = sm[t] - v;
  if (t == 0) *off_last = total;    // off[N] = E + N
}

__global__ void k_scanfinal(const int* __restrict__ deg, const int* __restrict__ bpre,
                            int* __restrict__ off, int* __restrict__ cursor, int N) {
  __shared__ int sm[256];
  int b = blockIdx.x, t = threadIdx.x;
  int base = b * 1024 + t * 4;
  int v[4];
  int s = 0;
#pragma unroll
  for (int j = 0; j < 4; ++j) {
    int i = base + j;
    v[j] = (i < N) ? deg[i] : 0;
    s += v[j];
  }
  sm[t] = s;
  __syncthreads();
  for (int o = 1; o < 256; o <<= 1) {
    int x = (t >= o) ? sm[t - o] : 0;
    __syncthreads();
    sm[t] += x;
    __syncthreads();
  }
  int run = bpre[b] + (sm[t] - s);
#pragma unroll
  for (int j = 0; j < 4; ++j) {
    int i = base + j;
    if (i < N) {
      off[i] = run;
      cursor[i] = run;
      run += v[j];
    }
  }
}

__global__ void k_scatter(const int* __restrict__ src, const int* __restrict__ dst,
                          int* __restrict__ cursor, int* __restrict__ csr,
                          int E, int N) {
  int idx = blockIdx.x * blockDim.x + threadIdx.x;
  if (idx >= E + N) return;
  int s, d;
  if (idx < E) { s = src[idx]; d = dst[idx]; }
  else         { s = d = idx - E; }            // self-loop
  int pos = atomicAdd(&cursor[d], 1);
  csr[pos] = s;
}

// ---------------------------------------------------------------- conversions
__global__ __launch_bounds__(256) void k_cvt_x(const float* __restrict__ x,
                                               unsigned short* __restrict__ xb,
                                               int n4) {
  for (int i = blockIdx.x * blockDim.x + threadIdx.x; i < n4;
       i += gridDim.x * blockDim.x) {
    float4 v = *reinterpret_cast<const float4*>(x + (size_t)i * 4);
    ushort4 o;
    o.x = f2b(v.x); o.y = f2b(v.y); o.z = f2b(v.z); o.w = f2b(v.w);
    *reinterpret_cast<ushort4*>(xb + (size_t)i * 4) = o;
  }
}

// Convert+transpose weights: W1[128][128] -> W1t[128][128] (col-major),
// W2[128][64] -> W2t[64][128].
__global__ __launch_bounds__(256) void k_prep_w(const float* __restrict__ W1,
                                                const float* __restrict__ W2,
                                                unsigned short* __restrict__ W1t,
                                                unsigned short* __restrict__ W2t) {
  int t = threadIdx.x;
  for (int o = t; o < 128 * 128; o += 256) {
    int n = o >> 7, k = o & 127;
    W1t[o] = f2b(W1[k * 128 + n]);
  }
  for (int o = t; o < 64 * 128; o += 256) {
    int n = o >> 7, k = o & 127;
    W2t[o] = f2b(W2[k * 64 + n]);
  }
}

// ---------------------------------------------------------------- MFMA GEMM
// C[N][COLS] = A[N][128] @ B[128][COLS], A,C bf16, Bt = B^T bf16 [COLS][128].
// Block: 256 threads (4 waves); tile 64 rows x COLS cols; K=128 in one shot.
// mfma_f32_16x16x32_bf16 lane layout: A[m=l&15][k=(l>>4)*8+j],
// B[k=(l>>4)*8+j][n=l&15], C col=l&15, row=(l>>4)*4+reg.
template <int COLS>
__global__ __launch_bounds__(256) void k_gemm_bf16(const unsigned short* __restrict__ A,
                                                   const unsigned short* __restrict__ Bt,
                                                   unsigned short* __restrict__ C,
                                                   int N) {
  constexpr int K = 128;
  constexpr int LDA = K + 8;                 // +16B pad: row stride 272B (68 dw ≡ 4 mod 32)
  __shared__ __align__(16) unsigned short As[64 * LDA];
  __shared__ __align__(16) unsigned short Bs[COLS * LDA];
  const int t = threadIdx.x;
  const int wave = t >> 6, lane = t & 63;
  const int row0 = blockIdx.x * 64;

  // stage A tile: 64 rows x 128 bf16 = 1024 x 16B chunks
#pragma unroll
  for (int i = 0; i < 4; ++i) {
    int c = t + 256 * i;
    int r = c >> 4, cq = c & 15;
    int4 v = make_int4(0, 0, 0, 0);
    if (row0 + r < N)
      v = *reinterpret_cast<const int4*>(A + (size_t)(row0 + r) * K + cq * 8);
    *reinterpret_cast<int4*>(&As[r * LDA + cq * 8]) = v;
  }
  // stage Bt: COLS rows x 128 bf16
#pragma unroll
  for (int i = 0; i < COLS / 16; ++i) {
    int c = t + 256 * i;
    int r = c >> 4, cq = c & 15;
    *reinterpret_cast<int4*>(&Bs[r * LDA + cq * 8]) =
        *reinterpret_cast<const int4*>(Bt + (size_t)r * K + cq * 8);
  }
  __syncthreads();

  const int m15 = lane & 15;
  const int koff = (lane >> 4) * 8;
  const int arow = wave * 16 + m15;

  f32x4 acc[COLS / 16];
#pragma unroll
  for (int ct = 0; ct < COLS / 16; ++ct) acc[ct] = (f32x4){0.f, 0.f, 0.f, 0.f};

#pragma unroll
  for (int kk = 0; kk < K / 32; ++kk) {
    short8 af = *reinterpret_cast<const short8*>(&As[arow * LDA + kk * 32 + koff]);
#pragma unroll
    for (int ct = 0; ct < COLS / 16; ++ct) {
      short8 bf = *reinterpret_cast<const short8*>(&Bs[(ct * 16 + m15) * LDA + kk * 32 + koff]);
      acc[ct] = __builtin_amdgcn_mfma_f32_16x16x32_bf16(af, bf, acc[ct], 0, 0, 0);
    }
  }

  // epilogue: bf16 store
#pragma unroll
  for (int ct = 0; ct < COLS / 16; ++ct) {
#pragma unroll
    for (int r = 0; r < 4; ++r) {
      int grow = row0 + wave * 16 + (lane >> 4) * 4 + r;
      if (grow < N)
        C[(size_t)grow * COLS + ct * 16 + m15] = f2b(acc[ct][r]);
    }
  }
}

// ---------------------------------------------------------------- alpha halves
template <int F>
__global__ __launch_bounds__(256) void k_alpha(const unsigned short* __restrict__ h,
                                               const float* __restrict__ a_src,
                                               const float* __restrict__ a_dst,
                                               float* __restrict__ as_,
                                               float* __restrict__ ad_, int N) {
  int wid = (blockIdx.x * blockDim.x + threadIdx.x) >> 6;
  int lane = threadIdx.x & 63;
  if (wid >= N) return;
  float ps = 0.f, pd = 0.f;
  if constexpr (F == 128) {
    unsigned int u = *reinterpret_cast<const unsigned int*>(h + (size_t)wid * 128 + 2 * lane);
    float v0 = b2f((unsigned short)(u & 0xffff));
    float v1 = b2f((unsigned short)(u >> 16));
    ps = v0 * a_src[2 * lane] + v1 * a_src[2 * lane + 1];
    pd = v0 * a_dst[2 * lane] + v1 * a_dst[2 * lane + 1];
  } else {
    float v = b2f(h[(size_t)wid * 64 + lane]);
    ps = v * a_src[lane];
    pd = v * a_dst[lane];
  }
  for (int o = 32; o; o >>= 1) {
    ps += __shfl_xor(ps, o);
    pd += __shfl_xor(pd, o);
  }
  if (lane == 0) {
    as_[wid] = ps;
    ad_[wid] = pd;
  }
}

// ---------------------------------------------------------------- aggregation
// One wave per destination node; 2 passes (no max-subtraction: logits are
// bounded |e| <~ 10, exp is safe in f32). OUT_BF16 selects bf16 vs f32 output.
template <int F, bool RELU, bool OUT_BF16>
__global__ __launch_bounds__(256) void k_agg(const int* __restrict__ off,
                                             const int* __restrict__ csr,
                                             const float* __restrict__ as_,
                                             const float* __restrict__ ad_,
                                             const unsigned short* __restrict__ h,
                                             const float* __restrict__ bias,
                                             void* __restrict__ outp, int N) {
  int wid = (blockIdx.x * blockDim.x + threadIdx.x) >> 6;
  int lane = threadIdx.x & 63;
  if (wid >= N) return;
  const int d = wid;
  const int s0 = off[d], s1 = off[d + 1];
  const float adv = ad_[d];

  // pass 1: denominator
  float lsum = 0.f;
  for (int base = s0; base < s1; base += 64) {
    int i = base + lane;
    if (i < s1) {
      float e = as_[csr[i]] + adv;
      e = (e > 0.f) ? e : LEAKY_SLOPE * e;
      lsum += __expf(e);
    }
  }
  for (int o = 32; o; o >>= 1) lsum += __shfl_xor(lsum, o);
  const float inv_s = 1.f / (lsum + 1e-16f);

  // pass 2: weighted gather of h[src]
  float acc0 = 0.f, acc1 = 0.f;
  for (int base = s0; base < s1; base += 64) {
    int i = base + lane;
    float w = 0.f;
    int sv = 0;
    if (i < s1) {
      sv = csr[i];
      float e = as_[sv] + adv;
      e = (e > 0.f) ? e : LEAKY_SLOPE * e;
      w = __expf(e) * inv_s;
    }
    const int jn = min(64, s1 - base);
    for (int j = 0; j < jn; ++j) {
      float wj = __int_as_float(__builtin_amdgcn_readlane(__float_as_int(w), j));
      int sj = __builtin_amdgcn_readlane(sv, j);
      if constexpr (F == 128) {
        unsigned int u = *reinterpret_cast<const unsigned int*>(h + (size_t)sj * 128 + 2 * lane);
        acc0 += wj * b2f((unsigned short)(u & 0xffff));
        acc1 += wj * b2f((unsigned short)(u >> 16));
      } else {
        acc0 += wj * b2f(h[(size_t)sj * 64 + lane]);
      }
    }
  }

  if constexpr (F == 128) {
    float o0 = acc0 + bias[2 * lane];
    float o1 = acc1 + bias[2 * lane + 1];
    if (RELU) { o0 = fmaxf(o0, 0.f); o1 = fmaxf(o1, 0.f); }
    if constexpr (OUT_BF16) {
      unsigned int pk = (unsigned int)f2b(o0) | ((unsigned int)f2b(o1) << 16);
      *reinterpret_cast<unsigned int*>((unsigned short*)outp + (size_t)d * 128 + 2 * lane) = pk;
    } else {
      *reinterpret_cast<float2*>((float*)outp + (size_t)d * 128 + 2 * lane) = make_float2(o0, o1);
    }
  } else {
    float o0 = acc0 + bias[lane];
    if (RELU) o0 = fmaxf(o0, 0.f);
    if constexpr (OUT_BF16) {
      ((unsigned short*)outp)[(size_t)d * 64 + lane] = f2b(o0);
    } else {
      ((float*)outp)[(size_t)d * 64 + lane] = o0;
    }
  }
}

// ---------------------------------------------------------------- final mean
__global__ __launch_bounds__(256) void k_mean(const float* __restrict__ out2,
                                              float* __restrict__ d_out, int N) {
  int c = threadIdx.x & 63;
  int w = threadIdx.x >> 6;                 // 0..3
  float acc = 0.f;
  for (int r = blockIdx.x * 4 + w; r < N; r += gridDim.x * 4)
    acc += out2[(size_t)r * 64 + c];
  atomicAdd(&d_out[c], acc * (1.0f / (float)N));
}

// ---------------------------------------------------------------- launch
extern "C" void kernel_launch(void* const* d_in, const int* in_sizes, int n_in,
                              void* d_out, int out_size, void* d_ws, size_t ws_size,
                              hipStream_t stream) {
  (void)n_in; (void)out_size; (void)ws_size;
  const float* x      = (const float*)d_in[0];
  const int*   edges  = (const int*)d_in[1];
  const float* W1     = (const float*)d_in[2];
  const float* a1_src = (const float*)d_in[3];
  const float* a1_dst = (const float*)d_in[4];
  const float* b1     = (const float*)d_in[5];
  const float* W2     = (const float*)d_in[6];
  const float* a2_src = (const float*)d_in[7];
  const float* a2_dst = (const float*)d_in[8];
  const float* b2     = (const float*)d_in[9];
  float* out = (float*)d_out;

  const int N = in_sizes[0] / 128;     // 100000
  const int E = in_sizes[1] / 2;       // 3200000
  const int ET = E + N;
  const int G = (N + 1023) / 1024;

  const int* e_src = edges;
  const int* e_dst = edges + E;

  char* ws = (char*)d_ws;
  size_t o = 0;
  auto alloc = [&](size_t bytes) {
    size_t p = o;
    o += (bytes + 511) & ~(size_t)511;
    return p;
  };
  unsigned short* xb  = (unsigned short*)(ws + alloc((size_t)N * 128 * 2));
  unsigned short* h1b = (unsigned short*)(ws + alloc((size_t)N * 128 * 2));
  unsigned short* g1b = (unsigned short*)(ws + alloc((size_t)N * 128 * 2));
  unsigned short* h2b = (unsigned short*)(ws + alloc((size_t)N * 64 * 2));
  float* out2   = (float*)(ws + alloc((size_t)N * 64 * 4));
  float* as1    = (float*)(ws + alloc((size_t)N * 4));
  float* ad1    = (float*)(ws + alloc((size_t)N * 4));
  float* as2    = (float*)(ws + alloc((size_t)N * 4));
  float* ad2    = (float*)(ws + alloc((size_t)N * 4));
  int*   off    = (int*)(ws + alloc((size_t)(N + 1) * 4));
  int*   cursor = (int*)(ws + alloc((size_t)N * 4));
  int*   deg    = (int*)(ws + alloc((size_t)N * 4));
  int*   bsum   = (int*)(ws + alloc((size_t)G * 4));
  int*   bpre   = (int*)(ws + alloc((size_t)G * 4));
  int*   csr    = (int*)(ws + alloc((size_t)ET * 4));
  unsigned short* W1t = (unsigned short*)(ws + alloc((size_t)128 * 128 * 2));
  unsigned short* W2t = (unsigned short*)(ws + alloc((size_t)64 * 128 * 2));

  // --- CSR build (shared by both layers) ---
  hipMemsetAsync(deg, 0, (size_t)N * 4, stream);
  {
    int blocks = (ET + 255) / 256;
    k_hist<<<blocks, 256, 0, stream>>>(e_dst, deg, E, N);
  }
  k_blocksum<<<G, 256, 0, stream>>>(deg, bsum, N);
  k_scanmid<<<1, 256, 0, stream>>>(bsum, bpre, G, ET, off + N);
  k_scanfinal<<<G, 256, 0, stream>>>(deg, bpre, off, cursor, N);
  {
    int blocks = (ET + 255) / 256;
    k_scatter<<<blocks, 256, 0, stream>>>(e_src, e_dst, cursor, csr, E, N);
  }

  // --- conversions ---
  k_cvt_x<<<1024, 256, 0, stream>>>(x, xb, N * 128 / 4);
  k_prep_w<<<1, 256, 0, stream>>>(W1, W2, W1t, W2t);

  const int gemm_grid = (N + 63) / 64;
  const int node_wave_grid = (N + 3) / 4;   // 4 waves per 256-thread block

  // --- layer 1 ---
  k_gemm_bf16<128><<<gemm_grid, 256, 0, stream>>>(xb, W1t, h1b, N);
  k_alpha<128><<<node_wave_grid, 256, 0, stream>>>(h1b, a1_src, a1_dst, as1, ad1, N);
  k_agg<128, true, true><<<node_wave_grid, 256, 0, stream>>>(off, csr, as1, ad1, h1b, b1, (void*)g1b, N);

  // --- layer 2 ---
  k_gemm_bf16<64><<<gemm_grid, 256, 0, stream>>>(g1b, W2t, h2b, N);
  k_alpha<64><<<node_wave_grid, 256, 0, stream>>>(h2b, a2_src, a2_dst, as2, ad2, N);
  k_agg<64, false, false><<<node_wave_grid, 256, 0, stream>>>(off, csr, as2, ad2, h2b, b2, (void*)out2, N);

  // --- mean over nodes ---
  hipMemsetAsync(out, 0, 64 * sizeof(float), stream);
  k_mean<<<256, 256, 0, stream>>>(out2, out, N);
}

// Round 3
// 715.169 us; speedup vs baseline: 1.5510x; 1.4131x over previous
//
#include <hip/hip_runtime.h>
#include <cstdint>
#include <cstddef>

#define LEAKY_SLOPE 0.2f

typedef __attribute__((ext_vector_type(8))) short short8;   // 8 x bf16 frag
typedef __attribute__((ext_vector_type(4))) float f32x4;

// ---- bf16 helpers (manual; RNE; inputs finite) ----
static __device__ inline unsigned short f2b(float f) {
  union { float f; unsigned int u; } c; c.f = f;
  unsigned int u = c.u;
  unsigned int r = (u + 0x7fffu + ((u >> 16) & 1u)) >> 16;
  return (unsigned short)r;
}
static __device__ inline float b2f(unsigned short b) {
  union { unsigned int u; float f; } c; c.u = ((unsigned int)b) << 16;
  return c.f;
}

// ================================================================ CSR build
// Two-level bucketed counting sort. Buckets of 256 nodes; every csr/staging
// cache line has a single-block owner -> write-combining in one XCD's L2.

// bucket histogram: gcount[b] = #edges with dst in bucket b
__global__ __launch_bounds__(256) void k_bhist(const int* __restrict__ dst,
                                               int* __restrict__ gcount,
                                               int E, int N, int NB) {
  __shared__ int lh[512];
  for (int i = threadIdx.x; i < NB; i += 256) lh[i] = 0;
  __syncthreads();
  int stride = gridDim.x * blockDim.x;
  for (int idx = blockIdx.x * blockDim.x + threadIdx.x; idx < E + N; idx += stride) {
    int d = (idx < E) ? dst[idx] : (idx - E);   // self-loops at tail
    atomicAdd(&lh[d >> 8], 1);
  }
  __syncthreads();
  for (int i = threadIdx.x; i < NB; i += 256)
    if (lh[i]) atomicAdd(&gcount[i], lh[i]);
}

// single-block exclusive scan of bucket counts (NB <= 512)
__global__ __launch_bounds__(512) void k_bscan(const int* __restrict__ gcount,
                                               int* __restrict__ gbase,
                                               int* __restrict__ gcursor,
                                               int NB, int ET, int* __restrict__ offN) {
  __shared__ int sm[512];
  int t = threadIdx.x;
  int v = (t < NB) ? gcount[t] : 0;
  sm[t] = v;
  __syncthreads();
  for (int o = 1; o < 512; o <<= 1) {
    int x = (t >= o) ? sm[t - o] : 0;
    __syncthreads();
    sm[t] += x;
    __syncthreads();
  }
  if (t < NB) {
    int b = sm[t] - v;
    gbase[t] = b;
    gcursor[t] = b;
  }
  if (t == 0) { gbase[NB] = ET; *offN = ET; }
}

// bin edges into bucket-grouped staging, packed (src<<8)|dst_local
template <int CHUNK>
__global__ __launch_bounds__(256) void k_binpass(const int* __restrict__ src,
                                                 const int* __restrict__ dst,
                                                 int* __restrict__ gcursor,
                                                 unsigned int* __restrict__ staging,
                                                 int E, int N, int NB) {
  __shared__ int lh[512];
  __shared__ int lbase[512];
  const int t = threadIdx.x;
  const int ET = E + N;
  const int e0 = blockIdx.x * CHUNK;
  const int e1 = min(e0 + CHUNK, ET);
  for (int i = t; i < NB; i += 256) lh[i] = 0;
  __syncthreads();
  for (int i = e0 + t; i < e1; i += 256) {
    int d = (i < E) ? dst[i] : (i - E);
    atomicAdd(&lh[d >> 8], 1);
  }
  __syncthreads();
  for (int i = t; i < NB; i += 256) {
    int c = lh[i];
    lbase[i] = c ? atomicAdd(&gcursor[i], c) : 0;
    lh[i] = 0;                       // reuse as local cursor
  }
  __syncthreads();
  for (int i = e0 + t; i < e1; i += 256) {
    int s, d;
    if (i < E) { s = src[i]; d = dst[i]; }
    else       { s = d = i - E; }
    int b = d >> 8;
    int r = atomicAdd(&lh[b], 1);
    staging[lbase[b] + r] = ((unsigned int)s << 8) | (unsigned int)(d & 255);
  }
}

// per-bucket CSR finalize: local deg/scan -> off[], scatter src -> csr
__global__ __launch_bounds__(256) void k_csrbuild(const int* __restrict__ gbase,
                                                  const unsigned int* __restrict__ staging,
                                                  int* __restrict__ off,
                                                  int* __restrict__ csr,
                                                  int N) {
  __shared__ int sc[256];
  __shared__ int cur[256];
  const int b = blockIdx.x, t = threadIdx.x;
  const int s0 = gbase[b], s1 = gbase[b + 1];
  cur[t] = 0;                        // use cur as deg first
  __syncthreads();
  for (int i = s0 + t; i < s1; i += 256)
    atomicAdd(&cur[staging[i] & 255], 1);
  __syncthreads();
  int v = cur[t];
  sc[t] = v;
  __syncthreads();
  for (int o = 1; o < 256; o <<= 1) {
    int x = (t >= o) ? sc[t - o] : 0;
    __syncthreads();
    sc[t] += x;
    __syncthreads();
  }
  int excl = s0 + sc[t] - v;
  int node = b * 256 + t;
  if (node < N) off[node] = excl;
  __syncthreads();                   // cur reused as cursor below
  cur[t] = excl;
  __syncthreads();
  for (int i = s0 + t; i < s1; i += 256) {
    unsigned int pv = staging[i];
    int slot = atomicAdd(&cur[pv & 255], 1);
    csr[slot] = (int)(pv >> 8);
  }
}

// ---------------------------------------------------------------- weights prep
__global__ __launch_bounds__(256) void k_prep_w(const float* __restrict__ W1,
                                                const float* __restrict__ W2,
                                                unsigned short* __restrict__ W1t,
                                                unsigned short* __restrict__ W2t) {
  int t = threadIdx.x;
  for (int o = t; o < 128 * 128; o += 256) {
    int n = o >> 7, k = o & 127;
    W1t[o] = f2b(W1[k * 128 + n]);
  }
  for (int o = t; o < 64 * 128; o += 256) {
    int n = o >> 7, k = o & 127;
    W2t[o] = f2b(W2[k * 64 + n]);
  }
}

// ---------------------------------------------------------------- MFMA GEMM
// C[N][COLS] = A[N][128] @ B[128][COLS]; A bf16 (or f32, converted on stage),
// Bt = B^T bf16 [COLS][128], C bf16.
template <int COLS, bool SRC_F32>
__global__ __launch_bounds__(256) void k_gemm_bf16(const void* __restrict__ Ap,
                                                   const unsigned short* __restrict__ Bt,
                                                   unsigned short* __restrict__ C,
                                                   int N) {
  constexpr int K = 128;
  constexpr int LDA = K + 8;
  __shared__ __align__(16) unsigned short As[64 * LDA];
  __shared__ __align__(16) unsigned short Bs[COLS * LDA];
  const int t = threadIdx.x;
  const int wave = t >> 6, lane = t & 63;
  const int row0 = blockIdx.x * 64;

#pragma unroll
  for (int i = 0; i < 4; ++i) {
    int c = t + 256 * i;
    int r = c >> 4, cq = c & 15;
    int4 v = make_int4(0, 0, 0, 0);
    if (row0 + r < N) {
      if constexpr (SRC_F32) {
        const float* Ar = (const float*)Ap + (size_t)(row0 + r) * K + cq * 8;
        float4 u = *reinterpret_cast<const float4*>(Ar);
        float4 w = *reinterpret_cast<const float4*>(Ar + 4);
        v.x = (int)f2b(u.x) | ((int)f2b(u.y) << 16);
        v.y = (int)f2b(u.z) | ((int)f2b(u.w) << 16);
        v.z = (int)f2b(w.x) | ((int)f2b(w.y) << 16);
        v.w = (int)f2b(w.z) | ((int)f2b(w.w) << 16);
      } else {
        v = *reinterpret_cast<const int4*>((const unsigned short*)Ap +
                                           (size_t)(row0 + r) * K + cq * 8);
      }
    }
    *reinterpret_cast<int4*>(&As[r * LDA + cq * 8]) = v;
  }
#pragma unroll
  for (int i = 0; i < COLS / 16; ++i) {
    int c = t + 256 * i;
    int r = c >> 4, cq = c & 15;
    *reinterpret_cast<int4*>(&Bs[r * LDA + cq * 8]) =
        *reinterpret_cast<const int4*>(Bt + (size_t)r * K + cq * 8);
  }
  __syncthreads();

  const int m15 = lane & 15;
  const int koff = (lane >> 4) * 8;
  const int arow = wave * 16 + m15;

  f32x4 acc[COLS / 16];
#pragma unroll
  for (int ct = 0; ct < COLS / 16; ++ct) acc[ct] = (f32x4){0.f, 0.f, 0.f, 0.f};

#pragma unroll
  for (int kk = 0; kk < K / 32; ++kk) {
    short8 af = *reinterpret_cast<const short8*>(&As[arow * LDA + kk * 32 + koff]);
#pragma unroll
    for (int ct = 0; ct < COLS / 16; ++ct) {
      short8 bf = *reinterpret_cast<const short8*>(&Bs[(ct * 16 + m15) * LDA + kk * 32 + koff]);
      acc[ct] = __builtin_amdgcn_mfma_f32_16x16x32_bf16(af, bf, acc[ct], 0, 0, 0);
    }
  }

#pragma unroll
  for (int ct = 0; ct < COLS / 16; ++ct) {
#pragma unroll
    for (int r = 0; r < 4; ++r) {
      int grow = row0 + wave * 16 + (lane >> 4) * 4 + r;
      if (grow < N)
        C[(size_t)grow * COLS + ct * 16 + m15] = f2b(acc[ct][r]);
    }
  }
}

// ---------------------------------------------------------------- alpha halves
template <int F>
__global__ __launch_bounds__(256) void k_alpha(const unsigned short* __restrict__ h,
                                               const float* __restrict__ a_src,
                                               const float* __restrict__ a_dst,
                                               float* __restrict__ as_,
                                               float* __restrict__ ad_, int N) {
  int wid = (blockIdx.x * blockDim.x + threadIdx.x) >> 6;
  int lane = threadIdx.x & 63;
  if (wid >= N) return;
  float ps = 0.f, pd = 0.f;
  if constexpr (F == 128) {
    unsigned int u = *reinterpret_cast<const unsigned int*>(h + (size_t)wid * 128 + 2 * lane);
    float v0 = b2f((unsigned short)(u & 0xffff));
    float v1 = b2f((unsigned short)(u >> 16));
    ps = v0 * a_src[2 * lane] + v1 * a_src[2 * lane + 1];
    pd = v0 * a_dst[2 * lane] + v1 * a_dst[2 * lane + 1];
  } else {
    float v = b2f(h[(size_t)wid * 64 + lane]);
    ps = v * a_src[lane];
    pd = v * a_dst[lane];
  }
  for (int o = 32; o; o >>= 1) {
    ps += __shfl_xor(ps, o);
    pd += __shfl_xor(pd, o);
  }
  if (lane == 0) {
    as_[wid] = ps;
    ad_[wid] = pd;
  }
}

// ---------------------------------------------------------------- aggregation
template <int F, bool RELU, bool OUT_BF16>
__global__ __launch_bounds__(256) void k_agg(const int* __restrict__ off,
                                             const int* __restrict__ csr,
                                             const float* __restrict__ as_,
                                             const float* __restrict__ ad_,
                                             const unsigned short* __restrict__ h,
                                             const float* __restrict__ bias,
                                             void* __restrict__ outp, int N) {
  int wid = (blockIdx.x * blockDim.x + threadIdx.x) >> 6;
  int lane = threadIdx.x & 63;
  if (wid >= N) return;
  const int d = wid;
  const int s0 = off[d], s1 = off[d + 1];
  const float adv = ad_[d];

  float lsum = 0.f;
  for (int base = s0; base < s1; base += 64) {
    int i = base + lane;
    if (i < s1) {
      float e = as_[csr[i]] + adv;
      e = (e > 0.f) ? e : LEAKY_SLOPE * e;
      lsum += __expf(e);
    }
  }
  for (int o = 32; o; o >>= 1) lsum += __shfl_xor(lsum, o);
  const float inv_s = 1.f / (lsum + 1e-16f);

  float acc0 = 0.f, acc1 = 0.f;
  for (int base = s0; base < s1; base += 64) {
    int i = base + lane;
    float w = 0.f;
    int sv = 0;
    if (i < s1) {
      sv = csr[i];
      float e = as_[sv] + adv;
      e = (e > 0.f) ? e : LEAKY_SLOPE * e;
      w = __expf(e) * inv_s;
    }
    const int jn = min(64, s1 - base);
    for (int j = 0; j < jn; ++j) {
      float wj = __int_as_float(__builtin_amdgcn_readlane(__float_as_int(w), j));
      int sj = __builtin_amdgcn_readlane(sv, j);
      if constexpr (F == 128) {
        unsigned int u = *reinterpret_cast<const unsigned int*>(h + (size_t)sj * 128 + 2 * lane);
        acc0 += wj * b2f((unsigned short)(u & 0xffff));
        acc1 += wj * b2f((unsigned short)(u >> 16));
      } else {
        acc0 += wj * b2f(h[(size_t)sj * 64 + lane]);
      }
    }
  }

  if constexpr (F == 128) {
    float o0 = acc0 + bias[2 * lane];
    float o1 = acc1 + bias[2 * lane + 1];
    if (RELU) { o0 = fmaxf(o0, 0.f); o1 = fmaxf(o1, 0.f); }
    if constexpr (OUT_BF16) {
      unsigned int pk = (unsigned int)f2b(o0) | ((unsigned int)f2b(o1) << 16);
      *reinterpret_cast<unsigned int*>((unsigned short*)outp + (size_t)d * 128 + 2 * lane) = pk;
    } else {
      *reinterpret_cast<float2*>((float*)outp + (size_t)d * 128 + 2 * lane) = make_float2(o0, o1);
    }
  } else {
    float o0 = acc0 + bias[lane];
    if (RELU) o0 = fmaxf(o0, 0.f);
    if constexpr (OUT_BF16) {
      ((unsigned short*)outp)[(size_t)d * 64 + lane] = f2b(o0);
    } else {
      ((float*)outp)[(size_t)d * 64 + lane] = o0;
    }
  }
}

// ---------------------------------------------------------------- final mean
__global__ __launch_bounds__(256) void k_mean(const float* __restrict__ out2,
                                              float* __restrict__ d_out, int N) {
  int c = threadIdx.x & 63;
  int w = threadIdx.x >> 6;
  float acc = 0.f;
  for (int r = blockIdx.x * 4 + w; r < N; r += gridDim.x * 4)
    acc += out2[(size_t)r * 64 + c];
  atomicAdd(&d_out[c], acc * (1.0f / (float)N));
}

// ---------------------------------------------------------------- launch
extern "C" void kernel_launch(void* const* d_in, const int* in_sizes, int n_in,
                              void* d_out, int out_size, void* d_ws, size_t ws_size,
                              hipStream_t stream) {
  (void)n_in; (void)out_size; (void)ws_size;
  const float* x      = (const float*)d_in[0];
  const int*   edges  = (const int*)d_in[1];
  const float* W1     = (const float*)d_in[2];
  const float* a1_src = (const float*)d_in[3];
  const float* a1_dst = (const float*)d_in[4];
  const float* b1     = (const float*)d_in[5];
  const float* W2     = (const float*)d_in[6];
  const float* a2_src = (const float*)d_in[7];
  const float* a2_dst = (const float*)d_in[8];
  const float* b2     = (const float*)d_in[9];
  float* out = (float*)d_out;

  const int N = in_sizes[0] / 128;     // 100000
  const int E = in_sizes[1] / 2;       // 3200000
  const int ET = E + N;
  const int NB = (N + 255) >> 8;       // 391 buckets of 256 nodes

  const int* e_src = edges;
  const int* e_dst = edges + E;

  char* ws = (char*)d_ws;
  size_t o = 0;
  auto alloc = [&](size_t bytes) {
    size_t p = o;
    o += (bytes + 511) & ~(size_t)511;
    return p;
  };
  unsigned short* h1b = (unsigned short*)(ws + alloc((size_t)N * 128 * 2));
  unsigned short* g1b = (unsigned short*)(ws + alloc((size_t)N * 128 * 2));
  unsigned short* h2b = (unsigned short*)(ws + alloc((size_t)N * 64 * 2));
  float* out2   = (float*)(ws + alloc((size_t)N * 64 * 4));
  float* as1    = (float*)(ws + alloc((size_t)N * 4));
  float* ad1    = (float*)(ws + alloc((size_t)N * 4));
  float* as2    = (float*)(ws + alloc((size_t)N * 4));
  float* ad2    = (float*)(ws + alloc((size_t)N * 4));
  int*   off    = (int*)(ws + alloc((size_t)(N + 1) * 4));
  int*   gcount = (int*)(ws + alloc((size_t)(NB + 1) * 4));
  int*   gbase  = (int*)(ws + alloc((size_t)(NB + 1) * 4));
  int*   gcursor= (int*)(ws + alloc((size_t)(NB + 1) * 4));
  unsigned int* staging = (unsigned int*)(ws + alloc((size_t)ET * 4));
  int*   csr    = (int*)(ws + alloc((size_t)ET * 4));
  unsigned short* W1t = (unsigned short*)(ws + alloc((size_t)128 * 128 * 2));
  unsigned short* W2t = (unsigned short*)(ws + alloc((size_t)64 * 128 * 2));

  // --- CSR build: bucketed counting sort ---
  hipMemsetAsync(gcount, 0, (size_t)NB * 4, stream);
  k_bhist<<<512, 256, 0, stream>>>(e_dst, gcount, E, N, NB);
  k_bscan<<<1, 512, 0, stream>>>(gcount, gbase, gcursor, NB, ET, off + N);
  constexpr int CHUNK = 8192;
  k_binpass<CHUNK><<<(ET + CHUNK - 1) / CHUNK, 256, 0, stream>>>(
      e_src, e_dst, gcursor, staging, E, N, NB);
  k_csrbuild<<<NB, 256, 0, stream>>>(gbase, staging, off, csr, N);

  // --- weights ---
  k_prep_w<<<1, 256, 0, stream>>>(W1, W2, W1t, W2t);

  const int gemm_grid = (N + 63) / 64;
  const int node_wave_grid = (N + 3) / 4;

  // --- layer 1 ---
  k_gemm_bf16<128, true><<<gemm_grid, 256, 0, stream>>>(x, W1t, h1b, N);
  k_alpha<128><<<node_wave_grid, 256, 0, stream>>>(h1b, a1_src, a1_dst, as1, ad1, N);
  k_agg<128, true, true><<<node_wave_grid, 256, 0, stream>>>(off, csr, as1, ad1, h1b, b1, (void*)g1b, N);

  // --- layer 2 ---
  k_gemm_bf16<64, false><<<gemm_grid, 256, 0, stream>>>(g1b, W2t, h2b, N);
  k_alpha<64><<<node_wave_grid, 256, 0, stream>>>(h2b, a2_src, a2_dst, as2, ad2, N);
  k_agg<64, false, false><<<node_wave_grid, 256, 0, stream>>>(off, csr, as2, ad2, h2b, b2, (void*)out2, N);

  // --- mean ---
  hipMemsetAsync(out, 0, 64 * sizeof(float), stream);
  k_mean<<<256, 256, 0, stream>>>(out2, out, N);
}

// Round 4
// 528.987 us; speedup vs baseline: 2.0969x; 1.3520x over previous
//
#include <hip/hip_runtime.h>
#include <cstdint>
#include <cstddef>

#define LEAKY_SLOPE 0.2f

typedef __attribute__((ext_vector_type(8))) short short8;   // 8 x bf16 frag
typedef __attribute__((ext_vector_type(4))) float f32x4;

// ---- bf16 helpers (manual; RNE; inputs finite) ----
static __device__ inline unsigned short f2b(float f) {
  union { float f; unsigned int u; } c; c.f = f;
  unsigned int u = c.u;
  unsigned int r = (u + 0x7fffu + ((u >> 16) & 1u)) >> 16;
  return (unsigned short)r;
}
static __device__ inline float b2f(unsigned short b) {
  union { unsigned int u; float f; } c; c.u = ((unsigned int)b) << 16;
  return c.f;
}
static __device__ inline float rdlane_f(float v, int j) {
  return __int_as_float(__builtin_amdgcn_readlane(__float_as_int(v), j));
}

// ================================================================ CSR build
__global__ __launch_bounds__(256) void k_bhist(const int* __restrict__ dst,
                                               int* __restrict__ gcount,
                                               int E, int N, int NB) {
  __shared__ int lh[512];
  for (int i = threadIdx.x; i < NB; i += 256) lh[i] = 0;
  __syncthreads();
  int stride = gridDim.x * blockDim.x;
  for (int idx = blockIdx.x * blockDim.x + threadIdx.x; idx < E + N; idx += stride) {
    int d = (idx < E) ? dst[idx] : (idx - E);   // self-loops at tail
    atomicAdd(&lh[d >> 8], 1);
  }
  __syncthreads();
  for (int i = threadIdx.x; i < NB; i += 256)
    if (lh[i]) atomicAdd(&gcount[i], lh[i]);
}

__global__ __launch_bounds__(512) void k_bscan(const int* __restrict__ gcount,
                                               int* __restrict__ gbase,
                                               int* __restrict__ gcursor,
                                               int NB, int ET, int* __restrict__ offN) {
  __shared__ int sm[512];
  int t = threadIdx.x;
  int v = (t < NB) ? gcount[t] : 0;
  sm[t] = v;
  __syncthreads();
  for (int o = 1; o < 512; o <<= 1) {
    int x = (t >= o) ? sm[t - o] : 0;
    __syncthreads();
    sm[t] += x;
    __syncthreads();
  }
  if (t < NB) {
    int b = sm[t] - v;
    gbase[t] = b;
    gcursor[t] = b;
  }
  if (t == 0) { gbase[NB] = ET; *offN = ET; }
}

template <int CHUNK>
__global__ __launch_bounds__(256) void k_binpass(const int* __restrict__ src,
                                                 const int* __restrict__ dst,
                                                 int* __restrict__ gcursor,
                                                 unsigned int* __restrict__ staging,
                                                 int E, int N, int NB) {
  __shared__ int lh[512];
  __shared__ int lbase[512];
  const int t = threadIdx.x;
  const int ET = E + N;
  const int e0 = blockIdx.x * CHUNK;
  const int e1 = min(e0 + CHUNK, ET);
  for (int i = t; i < NB; i += 256) lh[i] = 0;
  __syncthreads();
  for (int i = e0 + t; i < e1; i += 256) {
    int d = (i < E) ? dst[i] : (i - E);
    atomicAdd(&lh[d >> 8], 1);
  }
  __syncthreads();
  for (int i = t; i < NB; i += 256) {
    int c = lh[i];
    lbase[i] = c ? atomicAdd(&gcursor[i], c) : 0;
    lh[i] = 0;                       // reuse as local cursor
  }
  __syncthreads();
  for (int i = e0 + t; i < e1; i += 256) {
    int s, d;
    if (i < E) { s = src[i]; d = dst[i]; }
    else       { s = d = i - E; }
    int b = d >> 8;
    int r = atomicAdd(&lh[b], 1);
    staging[lbase[b] + r] = ((unsigned int)s << 8) | (unsigned int)(d & 255);
  }
}

__global__ __launch_bounds__(256) void k_csrbuild(const int* __restrict__ gbase,
                                                  const unsigned int* __restrict__ staging,
                                                  int* __restrict__ off,
                                                  int* __restrict__ csr,
                                                  int N) {
  __shared__ int sc[256];
  __shared__ int cur[256];
  const int b = blockIdx.x, t = threadIdx.x;
  const int s0 = gbase[b], s1 = gbase[b + 1];
  cur[t] = 0;
  __syncthreads();
  for (int i = s0 + t; i < s1; i += 256)
    atomicAdd(&cur[staging[i] & 255], 1);
  __syncthreads();
  int v = cur[t];
  sc[t] = v;
  __syncthreads();
  for (int o = 1; o < 256; o <<= 1) {
    int x = (t >= o) ? sc[t - o] : 0;
    __syncthreads();
    sc[t] += x;
    __syncthreads();
  }
  int excl = s0 + sc[t] - v;
  int node = b * 256 + t;
  if (node < N) off[node] = excl;
  __syncthreads();
  cur[t] = excl;
  __syncthreads();
  for (int i = s0 + t; i < s1; i += 256) {
    unsigned int pv = staging[i];
    int slot = atomicAdd(&cur[pv & 255], 1);
    csr[slot] = (int)(pv >> 8);
  }
}

// ---------------------------------------------------------------- weights prep
__global__ __launch_bounds__(256) void k_prep_w(const float* __restrict__ W1,
                                                const float* __restrict__ W2,
                                                unsigned short* __restrict__ W1t,
                                                unsigned short* __restrict__ W2t) {
  int t = threadIdx.x;
  for (int o = t; o < 128 * 128; o += 256) {
    int n = o >> 7, k = o & 127;
    W1t[o] = f2b(W1[k * 128 + n]);
  }
  for (int o = t; o < 64 * 128; o += 256) {
    int n = o >> 7, k = o & 127;
    W2t[o] = f2b(W2[k * 64 + n]);
  }
}

// ---------------------------------------------------------------- MFMA GEMM
template <int COLS, bool SRC_F32>
__global__ __launch_bounds__(256) void k_gemm_bf16(const void* __restrict__ Ap,
                                                   const unsigned short* __restrict__ Bt,
                                                   unsigned short* __restrict__ C,
                                                   int N) {
  constexpr int K = 128;
  constexpr int LDA = K + 8;
  __shared__ __align__(16) unsigned short As[64 * LDA];
  __shared__ __align__(16) unsigned short Bs[COLS * LDA];
  const int t = threadIdx.x;
  const int wave = t >> 6, lane = t & 63;
  const int row0 = blockIdx.x * 64;

#pragma unroll
  for (int i = 0; i < 4; ++i) {
    int c = t + 256 * i;
    int r = c >> 4, cq = c & 15;
    int4 v = make_int4(0, 0, 0, 0);
    if (row0 + r < N) {
      if constexpr (SRC_F32) {
        const float* Ar = (const float*)Ap + (size_t)(row0 + r) * K + cq * 8;
        float4 u = *reinterpret_cast<const float4*>(Ar);
        float4 w = *reinterpret_cast<const float4*>(Ar + 4);
        v.x = (int)f2b(u.x) | ((int)f2b(u.y) << 16);
        v.y = (int)f2b(u.z) | ((int)f2b(u.w) << 16);
        v.z = (int)f2b(w.x) | ((int)f2b(w.y) << 16);
        v.w = (int)f2b(w.z) | ((int)f2b(w.w) << 16);
      } else {
        v = *reinterpret_cast<const int4*>((const unsigned short*)Ap +
                                           (size_t)(row0 + r) * K + cq * 8);
      }
    }
    *reinterpret_cast<int4*>(&As[r * LDA + cq * 8]) = v;
  }
#pragma unroll
  for (int i = 0; i < COLS / 16; ++i) {
    int c = t + 256 * i;
    int r = c >> 4, cq = c & 15;
    *reinterpret_cast<int4*>(&Bs[r * LDA + cq * 8]) =
        *reinterpret_cast<const int4*>(Bt + (size_t)r * K + cq * 8);
  }
  __syncthreads();

  const int m15 = lane & 15;
  const int koff = (lane >> 4) * 8;
  const int arow = wave * 16 + m15;

  f32x4 acc[COLS / 16];
#pragma unroll
  for (int ct = 0; ct < COLS / 16; ++ct) acc[ct] = (f32x4){0.f, 0.f, 0.f, 0.f};

#pragma unroll
  for (int kk = 0; kk < K / 32; ++kk) {
    short8 af = *reinterpret_cast<const short8*>(&As[arow * LDA + kk * 32 + koff]);
#pragma unroll
    for (int ct = 0; ct < COLS / 16; ++ct) {
      short8 bf = *reinterpret_cast<const short8*>(&Bs[(ct * 16 + m15) * LDA + kk * 32 + koff]);
      acc[ct] = __builtin_amdgcn_mfma_f32_16x16x32_bf16(af, bf, acc[ct], 0, 0, 0);
    }
  }

#pragma unroll
  for (int ct = 0; ct < COLS / 16; ++ct) {
#pragma unroll
    for (int r = 0; r < 4; ++r) {
      int grow = row0 + wave * 16 + (lane >> 4) * 4 + r;
      if (grow < N)
        C[(size_t)grow * COLS + ct * 16 + m15] = f2b(acc[ct][r]);
    }
  }
}

// ---------------------------------------------------------------- alpha halves
template <int F>
__global__ __launch_bounds__(256) void k_alpha(const unsigned short* __restrict__ h,
                                               const float* __restrict__ a_src,
                                               const float* __restrict__ a_dst,
                                               float* __restrict__ as_,
                                               float* __restrict__ ad_, int N) {
  int wid = (blockIdx.x * blockDim.x + threadIdx.x) >> 6;
  int lane = threadIdx.x & 63;
  if (wid >= N) return;
  float ps = 0.f, pd = 0.f;
  if constexpr (F == 128) {
    unsigned int u = *reinterpret_cast<const unsigned int*>(h + (size_t)wid * 128 + 2 * lane);
    float v0 = b2f((unsigned short)(u & 0xffff));
    float v1 = b2f((unsigned short)(u >> 16));
    ps = v0 * a_src[2 * lane] + v1 * a_src[2 * lane + 1];
    pd = v0 * a_dst[2 * lane] + v1 * a_dst[2 * lane + 1];
  } else {
    float v = b2f(h[(size_t)wid * 64 + lane]);
    ps = v * a_src[lane];
    pd = v * a_dst[lane];
  }
  for (int o = 32; o; o >>= 1) {
    ps += __shfl_xor(ps, o);
    pd += __shfl_xor(pd, o);
  }
  if (lane == 0) {
    as_[wid] = ps;
    ad_[wid] = pd;
  }
}

// ---------------------------------------------------------------- aggregation
// One wave per dst node. Pass 2 gathers 8 h-rows concurrently (8 loads in
// flight per wave) to break the 1-outstanding-load latency serialization.
template <int F, bool RELU, bool OUT_BF16>
__global__ __launch_bounds__(256) void k_agg(const int* __restrict__ off,
                                             const int* __restrict__ csr,
                                             const float* __restrict__ as_,
                                             const float* __restrict__ ad_,
                                             const unsigned short* __restrict__ h,
                                             const float* __restrict__ bias,
                                             void* __restrict__ outp, int N) {
  int wid = (blockIdx.x * blockDim.x + threadIdx.x) >> 6;
  int lane = threadIdx.x & 63;
  if (wid >= N) return;
  const int d = wid;
  const int s0 = off[d], s1 = off[d + 1];
  const float adv = ad_[d];

  // pass 1: denominator
  float lsum = 0.f;
  for (int base = s0; base < s1; base += 64) {
    int i = base + lane;
    if (i < s1) {
      float e = as_[csr[i]] + adv;
      e = (e > 0.f) ? e : LEAKY_SLOPE * e;
      lsum += __expf(e);
    }
  }
  for (int o = 32; o; o >>= 1) lsum += __shfl_xor(lsum, o);
  const float inv_s = 1.f / (lsum + 1e-16f);

  // pass 2: weighted gather, 8-deep pipelined
  float acc0 = 0.f, acc1 = 0.f;
  const unsigned int* __restrict__ h32 = reinterpret_cast<const unsigned int*>(h);
  for (int base = s0; base < s1; base += 64) {
    int i = base + lane;
    float w = 0.f;
    int sv = 0;
    if (i < s1) {
      sv = csr[i];
      float e = as_[sv] + adv;
      e = (e > 0.f) ? e : LEAKY_SLOPE * e;
      w = __expf(e) * inv_s;
    }
    const int jn = min(64, s1 - base);
    int jj = 0;
    for (; jj + 8 <= jn; jj += 8) {
      int sj[8];
#pragma unroll
      for (int k = 0; k < 8; ++k)
        sj[k] = __builtin_amdgcn_readlane(sv, jj + k);
      if constexpr (F == 128) {
        unsigned int u[8];
#pragma unroll
        for (int k = 0; k < 8; ++k)
          u[k] = h32[(size_t)sj[k] * 64 + lane];      // 8 loads in flight
#pragma unroll
        for (int k = 0; k < 8; ++k) {
          float wj = rdlane_f(w, jj + k);
          acc0 += wj * b2f((unsigned short)(u[k] & 0xffff));
          acc1 += wj * b2f((unsigned short)(u[k] >> 16));
        }
      } else {
        unsigned short u[8];
#pragma unroll
        for (int k = 0; k < 8; ++k)
          u[k] = h[(size_t)sj[k] * 64 + lane];
#pragma unroll
        for (int k = 0; k < 8; ++k) {
          float wj = rdlane_f(w, jj + k);
          acc0 += wj * b2f(u[k]);
        }
      }
    }
    for (; jj < jn; ++jj) {
      float wj = rdlane_f(w, jj);
      int sj = __builtin_amdgcn_readlane(sv, jj);
      if constexpr (F == 128) {
        unsigned int u = h32[(size_t)sj * 64 + lane];
        acc0 += wj * b2f((unsigned short)(u & 0xffff));
        acc1 += wj * b2f((unsigned short)(u >> 16));
      } else {
        acc0 += wj * b2f(h[(size_t)sj * 64 + lane]);
      }
    }
  }

  if constexpr (F == 128) {
    float o0 = acc0 + bias[2 * lane];
    float o1 = acc1 + bias[2 * lane + 1];
    if (RELU) { o0 = fmaxf(o0, 0.f); o1 = fmaxf(o1, 0.f); }
    if constexpr (OUT_BF16) {
      unsigned int pk = (unsigned int)f2b(o0) | ((unsigned int)f2b(o1) << 16);
      *reinterpret_cast<unsigned int*>((unsigned short*)outp + (size_t)d * 128 + 2 * lane) = pk;
    } else {
      *reinterpret_cast<float2*>((float*)outp + (size_t)d * 128 + 2 * lane) = make_float2(o0, o1);
    }
  } else {
    float o0 = acc0 + bias[lane];
    if (RELU) o0 = fmaxf(o0, 0.f);
    if constexpr (OUT_BF16) {
      ((unsigned short*)outp)[(size_t)d * 64 + lane] = f2b(o0);
    } else {
      ((float*)outp)[(size_t)d * 64 + lane] = o0;
    }
  }
}

// ---------------------------------------------------------------- final mean
__global__ __launch_bounds__(256) void k_mean(const float* __restrict__ out2,
                                              float* __restrict__ d_out, int N) {
  int c = threadIdx.x & 63;
  int w = threadIdx.x >> 6;
  float acc = 0.f;
  for (int r = blockIdx.x * 4 + w; r < N; r += gridDim.x * 4)
    acc += out2[(size_t)r * 64 + c];
  atomicAdd(&d_out[c], acc * (1.0f / (float)N));
}

// ---------------------------------------------------------------- launch
extern "C" void kernel_launch(void* const* d_in, const int* in_sizes, int n_in,
                              void* d_out, int out_size, void* d_ws, size_t ws_size,
                              hipStream_t stream) {
  (void)n_in; (void)out_size; (void)ws_size;
  const float* x      = (const float*)d_in[0];
  const int*   edges  = (const int*)d_in[1];
  const float* W1     = (const float*)d_in[2];
  const float* a1_src = (const float*)d_in[3];
  const float* a1_dst = (const float*)d_in[4];
  const float* b1     = (const float*)d_in[5];
  const float* W2     = (const float*)d_in[6];
  const float* a2_src = (const float*)d_in[7];
  const float* a2_dst = (const float*)d_in[8];
  const float* b2     = (const float*)d_in[9];
  float* out = (float*)d_out;

  const int N = in_sizes[0] / 128;     // 100000
  const int E = in_sizes[1] / 2;       // 3200000
  const int ET = E + N;
  const int NB = (N + 255) >> 8;       // 391 buckets of 256 nodes

  const int* e_src = edges;
  const int* e_dst = edges + E;

  char* ws = (char*)d_ws;
  size_t o = 0;
  auto alloc = [&](size_t bytes) {
    size_t p = o;
    o += (bytes + 511) & ~(size_t)511;
    return p;
  };
  unsigned short* h1b = (unsigned short*)(ws + alloc((size_t)N * 128 * 2));
  unsigned short* g1b = (unsigned short*)(ws + alloc((size_t)N * 128 * 2));
  unsigned short* h2b = (unsigned short*)(ws + alloc((size_t)N * 64 * 2));
  float* out2   = (float*)(ws + alloc((size_t)N * 64 * 4));
  float* as1    = (float*)(ws + alloc((size_t)N * 4));
  float* ad1    = (float*)(ws + alloc((size_t)N * 4));
  float* as2    = (float*)(ws + alloc((size_t)N * 4));
  float* ad2    = (float*)(ws + alloc((size_t)N * 4));
  int*   off    = (int*)(ws + alloc((size_t)(N + 1) * 4));
  int*   gcount = (int*)(ws + alloc((size_t)(NB + 1) * 4));
  int*   gbase  = (int*)(ws + alloc((size_t)(NB + 1) * 4));
  int*   gcursor= (int*)(ws + alloc((size_t)(NB + 1) * 4));
  unsigned int* staging = (unsigned int*)(ws + alloc((size_t)ET * 4));
  int*   csr    = (int*)(ws + alloc((size_t)ET * 4));
  unsigned short* W1t = (unsigned short*)(ws + alloc((size_t)128 * 128 * 2));
  unsigned short* W2t = (unsigned short*)(ws + alloc((size_t)64 * 128 * 2));

  // --- CSR build: bucketed counting sort ---
  hipMemsetAsync(gcount, 0, (size_t)NB * 4, stream);
  k_bhist<<<512, 256, 0, stream>>>(e_dst, gcount, E, N, NB);
  k_bscan<<<1, 512, 0, stream>>>(gcount, gbase, gcursor, NB, ET, off + N);
  constexpr int CHUNK = 8192;
  k_binpass<CHUNK><<<(ET + CHUNK - 1) / CHUNK, 256, 0, stream>>>(
      e_src, e_dst, gcursor, staging, E, N, NB);
  k_csrbuild<<<NB, 256, 0, stream>>>(gbase, staging, off, csr, N);

  // --- weights ---
  k_prep_w<<<1, 256, 0, stream>>>(W1, W2, W1t, W2t);

  const int gemm_grid = (N + 63) / 64;
  const int node_wave_grid = (N + 3) / 4;

  // --- layer 1 ---
  k_gemm_bf16<128, true><<<gemm_grid, 256, 0, stream>>>(x, W1t, h1b, N);
  k_alpha<128><<<node_wave_grid, 256, 0, stream>>>(h1b, a1_src, a1_dst, as1, ad1, N);
  k_agg<128, true, true><<<node_wave_grid, 256, 0, stream>>>(off, csr, as1, ad1, h1b, b1, (void*)g1b, N);

  // --- layer 2 ---
  k_gemm_bf16<64, false><<<gemm_grid, 256, 0, stream>>>(g1b, W2t, h2b, N);
  k_alpha<64><<<node_wave_grid, 256, 0, stream>>>(h2b, a2_src, a2_dst, as2, ad2, N);
  k_agg<64, false, false><<<node_wave_grid, 256, 0, stream>>>(off, csr, as2, ad2, h2b, b2, (void*)out2, N);

  // --- mean ---
  hipMemsetAsync(out, 0, 64 * sizeof(float), stream);
  k_mean<<<256, 256, 0, stream>>>(out2, out, N);
}

// Round 5
// 477.938 us; speedup vs baseline: 2.3208x; 1.1068x over previous
//
#include <hip/hip_runtime.h>
#include <cstdint>
#include <cstddef>

#define LEAKY_SLOPE 0.2f

typedef __attribute__((ext_vector_type(8))) short short8;   // 8 x bf16 frag
typedef __attribute__((ext_vector_type(4))) float f32x4;

// ---- bf16 helpers (manual; RNE; inputs finite) ----
static __device__ inline unsigned short f2b(float f) {
  union { float f; unsigned int u; } c; c.f = f;
  unsigned int u = c.u;
  unsigned int r = (u + 0x7fffu + ((u >> 16) & 1u)) >> 16;
  return (unsigned short)r;
}
static __device__ inline float b2f(unsigned short b) {
  union { unsigned int u; float f; } c; c.u = ((unsigned int)b) << 16;
  return c.f;
}
static __device__ inline void fma8(float* acc, const int4 u, float w) {
  unsigned int d[4] = {(unsigned)u.x, (unsigned)u.y, (unsigned)u.z, (unsigned)u.w};
#pragma unroll
  for (int k = 0; k < 4; ++k) {
    acc[2 * k]     += w * b2f((unsigned short)(d[k] & 0xffffu));
    acc[2 * k + 1] += w * b2f((unsigned short)(d[k] >> 16));
  }
}

// ================================================================ CSR build
__global__ __launch_bounds__(256) void k_bhist(const int* __restrict__ dst,
                                               int* __restrict__ gcount,
                                               int E, int N, int NB) {
  __shared__ int lh[512];
  for (int i = threadIdx.x; i < NB; i += 256) lh[i] = 0;
  __syncthreads();
  int stride = gridDim.x * blockDim.x;
  for (int idx = blockIdx.x * blockDim.x + threadIdx.x; idx < E + N; idx += stride) {
    int d = (idx < E) ? dst[idx] : (idx - E);   // self-loops at tail
    atomicAdd(&lh[d >> 8], 1);
  }
  __syncthreads();
  for (int i = threadIdx.x; i < NB; i += 256)
    if (lh[i]) atomicAdd(&gcount[i], lh[i]);
}

__global__ __launch_bounds__(512) void k_bscan(const int* __restrict__ gcount,
                                               int* __restrict__ gbase,
                                               int* __restrict__ gcursor,
                                               int NB, int ET, int* __restrict__ offN) {
  __shared__ int sm[512];
  int t = threadIdx.x;
  int v = (t < NB) ? gcount[t] : 0;
  sm[t] = v;
  __syncthreads();
  for (int o = 1; o < 512; o <<= 1) {
    int x = (t >= o) ? sm[t - o] : 0;
    __syncthreads();
    sm[t] += x;
    __syncthreads();
  }
  if (t < NB) {
    int b = sm[t] - v;
    gbase[t] = b;
    gcursor[t] = b;
  }
  if (t == 0) { gbase[NB] = ET; *offN = ET; }
}

template <int CHUNK>
__global__ __launch_bounds__(256) void k_binpass(const int* __restrict__ src,
                                                 const int* __restrict__ dst,
                                                 int* __restrict__ gcursor,
                                                 unsigned int* __restrict__ staging,
                                                 int E, int N, int NB) {
  __shared__ int lh[512];
  __shared__ int lbase[512];
  const int t = threadIdx.x;
  const int ET = E + N;
  const int e0 = blockIdx.x * CHUNK;
  const int e1 = min(e0 + CHUNK, ET);
  for (int i = t; i < NB; i += 256) lh[i] = 0;
  __syncthreads();
  for (int i = e0 + t; i < e1; i += 256) {
    int d = (i < E) ? dst[i] : (i - E);
    atomicAdd(&lh[d >> 8], 1);
  }
  __syncthreads();
  for (int i = t; i < NB; i += 256) {
    int c = lh[i];
    lbase[i] = c ? atomicAdd(&gcursor[i], c) : 0;
    lh[i] = 0;                       // reuse as local cursor
  }
  __syncthreads();
  for (int i = e0 + t; i < e1; i += 256) {
    int s, d;
    if (i < E) { s = src[i]; d = dst[i]; }
    else       { s = d = i - E; }
    int b = d >> 8;
    int r = atomicAdd(&lh[b], 1);
    staging[lbase[b] + r] = ((unsigned int)s << 8) | (unsigned int)(d & 255);
  }
}

__global__ __launch_bounds__(256) void k_csrbuild(const int* __restrict__ gbase,
                                                  const unsigned int* __restrict__ staging,
                                                  int* __restrict__ off,
                                                  int* __restrict__ csr,
                                                  int N) {
  __shared__ int sc[256];
  __shared__ int cur[256];
  const int b = blockIdx.x, t = threadIdx.x;
  const int s0 = gbase[b], s1 = gbase[b + 1];
  cur[t] = 0;
  __syncthreads();
  for (int i = s0 + t; i < s1; i += 256)
    atomicAdd(&cur[staging[i] & 255], 1);
  __syncthreads();
  int v = cur[t];
  sc[t] = v;
  __syncthreads();
  for (int o = 1; o < 256; o <<= 1) {
    int x = (t >= o) ? sc[t - o] : 0;
    __syncthreads();
    sc[t] += x;
    __syncthreads();
  }
  int excl = s0 + sc[t] - v;
  int node = b * 256 + t;
  if (node < N) off[node] = excl;
  __syncthreads();
  cur[t] = excl;
  __syncthreads();
  for (int i = s0 + t; i < s1; i += 256) {
    unsigned int pv = staging[i];
    int slot = atomicAdd(&cur[pv & 255], 1);
    csr[slot] = (int)(pv >> 8);
  }
}

// ---------------------------------------------------------------- weights prep
__global__ __launch_bounds__(256) void k_prep_w(const float* __restrict__ W1,
                                                const float* __restrict__ W2,
                                                unsigned short* __restrict__ W1t,
                                                unsigned short* __restrict__ W2t) {
  int t = threadIdx.x;
  for (int o = t; o < 128 * 128; o += 256) {
    int n = o >> 7, k = o & 127;
    W1t[o] = f2b(W1[k * 128 + n]);
  }
  for (int o = t; o < 64 * 128; o += 256) {
    int n = o >> 7, k = o & 127;
    W2t[o] = f2b(W2[k * 64 + n]);
  }
}

// ---------------------------------------------------------------- MFMA GEMM
// C[N][COLS] = A[N][128] @ B[128][COLS]; fused alpha epilogue:
// as_[row] = C_row . av_src, ad_[row] = C_row . av_dst (on f32 acc).
template <int COLS, bool SRC_F32>
__global__ __launch_bounds__(256) void k_gemm_bf16(const void* __restrict__ Ap,
                                                   const unsigned short* __restrict__ Bt,
                                                   unsigned short* __restrict__ C,
                                                   const float* __restrict__ av_src,
                                                   const float* __restrict__ av_dst,
                                                   float* __restrict__ as_,
                                                   float* __restrict__ ad_,
                                                   int N) {
  constexpr int K = 128;
  constexpr int LDA = K + 8;
  __shared__ __align__(16) unsigned short As[64 * LDA];
  __shared__ __align__(16) unsigned short Bs[COLS * LDA];
  const int t = threadIdx.x;
  const int wave = t >> 6, lane = t & 63;
  const int row0 = blockIdx.x * 64;

#pragma unroll
  for (int i = 0; i < 4; ++i) {
    int c = t + 256 * i;
    int r = c >> 4, cq = c & 15;
    int4 v = make_int4(0, 0, 0, 0);
    if (row0 + r < N) {
      if constexpr (SRC_F32) {
        const float* Ar = (const float*)Ap + (size_t)(row0 + r) * K + cq * 8;
        float4 u = *reinterpret_cast<const float4*>(Ar);
        float4 w = *reinterpret_cast<const float4*>(Ar + 4);
        v.x = (int)f2b(u.x) | ((int)f2b(u.y) << 16);
        v.y = (int)f2b(u.z) | ((int)f2b(u.w) << 16);
        v.z = (int)f2b(w.x) | ((int)f2b(w.y) << 16);
        v.w = (int)f2b(w.z) | ((int)f2b(w.w) << 16);
      } else {
        v = *reinterpret_cast<const int4*>((const unsigned short*)Ap +
                                           (size_t)(row0 + r) * K + cq * 8);
      }
    }
    *reinterpret_cast<int4*>(&As[r * LDA + cq * 8]) = v;
  }
#pragma unroll
  for (int i = 0; i < COLS / 16; ++i) {
    int c = t + 256 * i;
    int r = c >> 4, cq = c & 15;
    *reinterpret_cast<int4*>(&Bs[r * LDA + cq * 8]) =
        *reinterpret_cast<const int4*>(Bt + (size_t)r * K + cq * 8);
  }
  __syncthreads();

  const int m15 = lane & 15;
  const int koff = (lane >> 4) * 8;
  const int arow = wave * 16 + m15;

  f32x4 acc[COLS / 16];
#pragma unroll
  for (int ct = 0; ct < COLS / 16; ++ct) acc[ct] = (f32x4){0.f, 0.f, 0.f, 0.f};

#pragma unroll
  for (int kk = 0; kk < K / 32; ++kk) {
    short8 af = *reinterpret_cast<const short8*>(&As[arow * LDA + kk * 32 + koff]);
#pragma unroll
    for (int ct = 0; ct < COLS / 16; ++ct) {
      short8 bf = *reinterpret_cast<const short8*>(&Bs[(ct * 16 + m15) * LDA + kk * 32 + koff]);
      acc[ct] = __builtin_amdgcn_mfma_f32_16x16x32_bf16(af, bf, acc[ct], 0, 0, 0);
    }
  }

  // C store (bf16)
#pragma unroll
  for (int ct = 0; ct < COLS / 16; ++ct) {
#pragma unroll
    for (int r = 0; r < 4; ++r) {
      int grow = row0 + wave * 16 + (lane >> 4) * 4 + r;
      if (grow < N)
        C[(size_t)grow * COLS + ct * 16 + m15] = f2b(acc[ct][r]);
    }
  }

  // fused alpha epilogue
  {
    float ps[4] = {0.f, 0.f, 0.f, 0.f}, pd[4] = {0.f, 0.f, 0.f, 0.f};
#pragma unroll
    for (int ct = 0; ct < COLS / 16; ++ct) {
      float av = av_src[ct * 16 + m15];
      float bv = av_dst[ct * 16 + m15];
#pragma unroll
      for (int r = 0; r < 4; ++r) {
        ps[r] += acc[ct][r] * av;
        pd[r] += acc[ct][r] * bv;
      }
    }
#pragma unroll
    for (int o = 1; o < 16; o <<= 1) {
#pragma unroll
      for (int r = 0; r < 4; ++r) {
        ps[r] += __shfl_xor(ps[r], o);
        pd[r] += __shfl_xor(pd[r], o);
      }
    }
    if (m15 == 0) {
#pragma unroll
      for (int r = 0; r < 4; ++r) {
        int grow = row0 + wave * 16 + (lane >> 4) * 4 + r;
        if (grow < N) { as_[grow] = ps[r]; ad_[grow] = pd[r]; }
      }
    }
  }
}

// ---------------------------------------------------------------- aggregation
// One wave per dst node, single pass:
//   out = (sum_j exp(e_j) h[src_j]) / sum_j exp(e_j)  (+bias, opt ReLU)
// Each lane gathers int4 (8 bf16) => wave covers GPI=64/(F/8) rows per load.
// Per-group weight/index via variable-lane shfl; 4 groups in flight.
template <int F, bool RELU, bool OUT_BF16>
__global__ __launch_bounds__(256) void k_agg(const int* __restrict__ off,
                                             const int* __restrict__ csr,
                                             const float* __restrict__ as_,
                                             const float* __restrict__ ad_,
                                             const unsigned short* __restrict__ h,
                                             const float* __restrict__ bias,
                                             void* __restrict__ outp, int N) {
  constexpr int LPR = F / 8;      // lanes per row (16 or 8)
  constexpr int GPI = 64 / LPR;   // rows per load wave-wide (4 or 8)
  int wid = (blockIdx.x * blockDim.x + threadIdx.x) >> 6;
  int lane = threadIdx.x & 63;
  if (wid >= N) return;
  const int s0 = off[wid], s1 = off[wid + 1];
  const float adv = ad_[wid];
  const int g  = lane / LPR;
  const int fl = lane % LPR;
  const unsigned short* hb = h + (size_t)fl * 8;

  float acc[8] = {0.f, 0.f, 0.f, 0.f, 0.f, 0.f, 0.f, 0.f};
  float lsum = 0.f;

  for (int base = s0; base < s1; base += 64) {
    int i = base + lane;
    int sv = 0;
    float wexp = 0.f;
    if (i < s1) {
      sv = csr[i];
      float e = as_[sv] + adv;
      e = (e > 0.f) ? e : LEAKY_SLOPE * e;
      wexp = __expf(e);
      lsum += wexp;
    }
    const int jn = min(64, s1 - base);
    int jj = 0;
    // 4 row-groups in flight (srclane max provably <= 63)
    for (; jj + 4 * GPI <= jn; jj += 4 * GPI) {
      int sl = jj + g;
      int sj0 = __shfl(sv, sl);
      int sj1 = __shfl(sv, sl + GPI);
      int sj2 = __shfl(sv, sl + 2 * GPI);
      int sj3 = __shfl(sv, sl + 3 * GPI);
      float w0 = __shfl(wexp, sl);
      float w1 = __shfl(wexp, sl + GPI);
      float w2 = __shfl(wexp, sl + 2 * GPI);
      float w3 = __shfl(wexp, sl + 3 * GPI);
      int4 u0 = *reinterpret_cast<const int4*>(hb + (size_t)sj0 * F);
      int4 u1 = *reinterpret_cast<const int4*>(hb + (size_t)sj1 * F);
      int4 u2 = *reinterpret_cast<const int4*>(hb + (size_t)sj2 * F);
      int4 u3 = *reinterpret_cast<const int4*>(hb + (size_t)sj3 * F);
      fma8(acc, u0, w0);
      fma8(acc, u1, w1);
      fma8(acc, u2, w2);
      fma8(acc, u3, w3);
    }
    for (; jj < jn; jj += GPI) {
      int sl = jj + g;                 // <= 63 always; zero-weight slack ok
      int sj0 = __shfl(sv, sl);
      float w0 = __shfl(wexp, sl);
      int4 u0 = *reinterpret_cast<const int4*>(hb + (size_t)sj0 * F);
      fma8(acc, u0, w0);
    }
  }

  // denominator
  for (int o = 32; o; o >>= 1) lsum += __shfl_xor(lsum, o);
  const float inv_s = 1.f / (lsum + 1e-16f);

  // cross-group feature reduction
#pragma unroll
  for (int o = LPR; o < 64; o <<= 1) {
#pragma unroll
    for (int k = 0; k < 8; ++k) acc[k] += __shfl_xor(acc[k], o);
  }

  if (g == 0) {
    float ov[8];
#pragma unroll
    for (int k = 0; k < 8; ++k) {
      ov[k] = acc[k] * inv_s + bias[fl * 8 + k];
      if (RELU) ov[k] = fmaxf(ov[k], 0.f);
    }
    if constexpr (OUT_BF16) {
      int4 pk;
      pk.x = (int)f2b(ov[0]) | ((int)f2b(ov[1]) << 16);
      pk.y = (int)f2b(ov[2]) | ((int)f2b(ov[3]) << 16);
      pk.z = (int)f2b(ov[4]) | ((int)f2b(ov[5]) << 16);
      pk.w = (int)f2b(ov[6]) | ((int)f2b(ov[7]) << 16);
      *reinterpret_cast<int4*>((unsigned short*)outp + (size_t)wid * F + fl * 8) = pk;
    } else {
      float* op = (float*)outp + (size_t)wid * F + fl * 8;
      *reinterpret_cast<float4*>(op) = make_float4(ov[0], ov[1], ov[2], ov[3]);
      *reinterpret_cast<float4*>(op + 4) = make_float4(ov[4], ov[5], ov[6], ov[7]);
    }
  }
}

// ---------------------------------------------------------------- final mean
__global__ __launch_bounds__(256) void k_mean(const float* __restrict__ out2,
                                              float* __restrict__ d_out, int N) {
  int c = threadIdx.x & 63;
  int w = threadIdx.x >> 6;
  float acc = 0.f;
  for (int r = blockIdx.x * 4 + w; r < N; r += gridDim.x * 4)
    acc += out2[(size_t)r * 64 + c];
  atomicAdd(&d_out[c], acc * (1.0f / (float)N));
}

// ---------------------------------------------------------------- launch
extern "C" void kernel_launch(void* const* d_in, const int* in_sizes, int n_in,
                              void* d_out, int out_size, void* d_ws, size_t ws_size,
                              hipStream_t stream) {
  (void)n_in; (void)out_size; (void)ws_size;
  const float* x      = (const float*)d_in[0];
  const int*   edges  = (const int*)d_in[1];
  const float* W1     = (const float*)d_in[2];
  const float* a1_src = (const float*)d_in[3];
  const float* a1_dst = (const float*)d_in[4];
  const float* b1     = (const float*)d_in[5];
  const float* W2     = (const float*)d_in[6];
  const float* a2_src = (const float*)d_in[7];
  const float* a2_dst = (const float*)d_in[8];
  const float* b2     = (const float*)d_in[9];
  float* out = (float*)d_out;

  const int N = in_sizes[0] / 128;     // 100000
  const int E = in_sizes[1] / 2;       // 3200000
  const int ET = E + N;
  const int NB = (N + 255) >> 8;       // 391 buckets of 256 nodes

  const int* e_src = edges;
  const int* e_dst = edges + E;

  char* ws = (char*)d_ws;
  size_t o = 0;
  auto alloc = [&](size_t bytes) {
    size_t p = o;
    o += (bytes + 511) & ~(size_t)511;
    return p;
  };
  unsigned short* h1b = (unsigned short*)(ws + alloc((size_t)N * 128 * 2));
  unsigned short* g1b = (unsigned short*)(ws + alloc((size_t)N * 128 * 2));
  unsigned short* h2b = (unsigned short*)(ws + alloc((size_t)N * 64 * 2));
  float* out2   = (float*)(ws + alloc((size_t)N * 64 * 4));
  float* as1    = (float*)(ws + alloc((size_t)N * 4));
  float* ad1    = (float*)(ws + alloc((size_t)N * 4));
  float* as2    = (float*)(ws + alloc((size_t)N * 4));
  float* ad2    = (float*)(ws + alloc((size_t)N * 4));
  int*   off    = (int*)(ws + alloc((size_t)(N + 1) * 4));
  int*   gcount = (int*)(ws + alloc((size_t)(NB + 1) * 4));
  int*   gbase  = (int*)(ws + alloc((size_t)(NB + 1) * 4));
  int*   gcursor= (int*)(ws + alloc((size_t)(NB + 1) * 4));
  unsigned int* staging = (unsigned int*)(ws + alloc((size_t)ET * 4));
  int*   csr    = (int*)(ws + alloc((size_t)ET * 4));
  unsigned short* W1t = (unsigned short*)(ws + alloc((size_t)128 * 128 * 2));
  unsigned short* W2t = (unsigned short*)(ws + alloc((size_t)64 * 128 * 2));

  // --- CSR build: bucketed counting sort ---
  hipMemsetAsync(gcount, 0, (size_t)NB * 4, stream);
  k_bhist<<<512, 256, 0, stream>>>(e_dst, gcount, E, N, NB);
  k_bscan<<<1, 512, 0, stream>>>(gcount, gbase, gcursor, NB, ET, off + N);
  constexpr int CHUNK = 8192;
  k_binpass<CHUNK><<<(ET + CHUNK - 1) / CHUNK, 256, 0, stream>>>(
      e_src, e_dst, gcursor, staging, E, N, NB);
  k_csrbuild<<<NB, 256, 0, stream>>>(gbase, staging, off, csr, N);

  // --- weights ---
  k_prep_w<<<1, 256, 0, stream>>>(W1, W2, W1t, W2t);

  const int gemm_grid = (N + 63) / 64;
  const int node_wave_grid = (N + 3) / 4;

  // --- layer 1 (GEMM + fused alpha, then single-pass agg) ---
  k_gemm_bf16<128, true><<<gemm_grid, 256, 0, stream>>>(
      x, W1t, h1b, a1_src, a1_dst, as1, ad1, N);
  k_agg<128, true, true><<<node_wave_grid, 256, 0, stream>>>(
      off, csr, as1, ad1, h1b, b1, (void*)g1b, N);

  // --- layer 2 ---
  k_gemm_bf16<64, false><<<gemm_grid, 256, 0, stream>>>(
      g1b, W2t, h2b, a2_src, a2_dst, as2, ad2, N);
  k_agg<64, false, false><<<node_wave_grid, 256, 0, stream>>>(
      off, csr, as2, ad2, h2b, b2, (void*)out2, N);

  // --- mean ---
  hipMemsetAsync(out, 0, 64 * sizeof(float), stream);
  k_mean<<<256, 256, 0, stream>>>(out2, out, N);
}

// Round 6
// 445.291 us; speedup vs baseline: 2.4910x; 1.0733x over previous
//
#include <hip/hip_runtime.h>
#include <cstdint>
#include <cstddef>

#define LEAKY_SLOPE 0.2f

typedef __attribute__((ext_vector_type(8))) short short8;   // 8 x bf16 frag
typedef __attribute__((ext_vector_type(4))) float f32x4;

// ---- bf16 helpers (manual; RNE; inputs finite) ----
static __device__ inline unsigned short f2b(float f) {
  union { float f; unsigned int u; } c; c.f = f;
  unsigned int u = c.u;
  unsigned int r = (u + 0x7fffu + ((u >> 16) & 1u)) >> 16;
  return (unsigned short)r;
}
static __device__ inline float b2f(unsigned short b) {
  union { unsigned int u; float f; } c; c.u = ((unsigned int)b) << 16;
  return c.f;
}
// fp8 e4m3 (self-consistent encode/decode via HW cvt)
static __device__ inline unsigned char f2f8(float v) {
  int pk = __builtin_amdgcn_cvt_pk_fp8_f32(v, v, 0, false);
  return (unsigned char)(pk & 0xff);
}
static __device__ inline void fma8f8(float* acc, uint2 u, float w) {
  auto a = __builtin_amdgcn_cvt_pk_f32_fp8(u.x, false);
  auto b = __builtin_amdgcn_cvt_pk_f32_fp8(u.x, true);
  auto c = __builtin_amdgcn_cvt_pk_f32_fp8(u.y, false);
  auto d = __builtin_amdgcn_cvt_pk_f32_fp8(u.y, true);
  acc[0] += w * a[0]; acc[1] += w * a[1];
  acc[2] += w * b[0]; acc[3] += w * b[1];
  acc[4] += w * c[0]; acc[5] += w * c[1];
  acc[6] += w * d[0]; acc[7] += w * d[1];
}

// ================================================================ CSR build
__global__ __launch_bounds__(256) void k_bhist(const int* __restrict__ dst,
                                               int* __restrict__ gcount,
                                               int E, int N, int NB) {
  __shared__ int lh[512];
  for (int i = threadIdx.x; i < NB; i += 256) lh[i] = 0;
  __syncthreads();
  int stride = gridDim.x * blockDim.x;
  for (int idx = blockIdx.x * blockDim.x + threadIdx.x; idx < E + N; idx += stride) {
    int d = (idx < E) ? dst[idx] : (idx - E);   // self-loops at tail
    atomicAdd(&lh[d >> 8], 1);
  }
  __syncthreads();
  for (int i = threadIdx.x; i < NB; i += 256)
    if (lh[i]) atomicAdd(&gcount[i], lh[i]);
}

__global__ __launch_bounds__(512) void k_bscan(const int* __restrict__ gcount,
                                               int* __restrict__ gbase,
                                               int* __restrict__ gcursor,
                                               int NB, int ET, int* __restrict__ offN) {
  __shared__ int sm[512];
  int t = threadIdx.x;
  int v = (t < NB) ? gcount[t] : 0;
  sm[t] = v;
  __syncthreads();
  for (int o = 1; o < 512; o <<= 1) {
    int x = (t >= o) ? sm[t - o] : 0;
    __syncthreads();
    sm[t] += x;
    __syncthreads();
  }
  if (t < NB) {
    int b = sm[t] - v;
    gbase[t] = b;
    gcursor[t] = b;
  }
  if (t == 0) { gbase[NB] = ET; *offN = ET; }
}

template <int CHUNK>
__global__ __launch_bounds__(256) void k_binpass(const int* __restrict__ src,
                                                 const int* __restrict__ dst,
                                                 int* __restrict__ gcursor,
                                                 unsigned int* __restrict__ staging,
                                                 int E, int N, int NB) {
  __shared__ int lh[512];
  __shared__ int lbase[512];
  const int t = threadIdx.x;
  const int ET = E + N;
  const int e0 = blockIdx.x * CHUNK;
  const int e1 = min(e0 + CHUNK, ET);
  for (int i = t; i < NB; i += 256) lh[i] = 0;
  __syncthreads();
  for (int i = e0 + t; i < e1; i += 256) {
    int d = (i < E) ? dst[i] : (i - E);
    atomicAdd(&lh[d >> 8], 1);
  }
  __syncthreads();
  for (int i = t; i < NB; i += 256) {
    int c = lh[i];
    lbase[i] = c ? atomicAdd(&gcursor[i], c) : 0;
    lh[i] = 0;                       // reuse as local cursor
  }
  __syncthreads();
  for (int i = e0 + t; i < e1; i += 256) {
    int s, d;
    if (i < E) { s = src[i]; d = dst[i]; }
    else       { s = d = i - E; }
    int b = d >> 8;
    int r = atomicAdd(&lh[b], 1);
    staging[lbase[b] + r] = ((unsigned int)s << 8) | (unsigned int)(d & 255);
  }
}

__global__ __launch_bounds__(256) void k_csrbuild(const int* __restrict__ gbase,
                                                  const unsigned int* __restrict__ staging,
                                                  int* __restrict__ off,
                                                  int* __restrict__ csr,
                                                  int N) {
  __shared__ int sc[256];
  __shared__ int cur[256];
  const int b = blockIdx.x, t = threadIdx.x;
  const int s0 = gbase[b], s1 = gbase[b + 1];
  cur[t] = 0;
  __syncthreads();
  for (int i = s0 + t; i < s1; i += 256)
    atomicAdd(&cur[staging[i] & 255], 1);
  __syncthreads();
  int v = cur[t];
  sc[t] = v;
  __syncthreads();
  for (int o = 1; o < 256; o <<= 1) {
    int x = (t >= o) ? sc[t - o] : 0;
    __syncthreads();
    sc[t] += x;
    __syncthreads();
  }
  int excl = s0 + sc[t] - v;
  int node = b * 256 + t;
  if (node < N) off[node] = excl;
  __syncthreads();
  cur[t] = excl;
  __syncthreads();
  for (int i = s0 + t; i < s1; i += 256) {
    unsigned int pv = staging[i];
    int slot = atomicAdd(&cur[pv & 255], 1);
    csr[slot] = (int)(pv >> 8);
  }
}

// ---------------------------------------------------------------- weights prep
__global__ __launch_bounds__(256) void k_prep_w(const float* __restrict__ W1,
                                                const float* __restrict__ W2,
                                                unsigned short* __restrict__ W1t,
                                                unsigned short* __restrict__ W2t) {
  int t = threadIdx.x;
  for (int o = t; o < 128 * 128; o += 256) {
    int n = o >> 7, k = o & 127;
    W1t[o] = f2b(W1[k * 128 + n]);
  }
  for (int o = t; o < 64 * 128; o += 256) {
    int n = o >> 7, k = o & 127;
    W2t[o] = f2b(W2[k * 64 + n]);
  }
}

// ---------------------------------------------------------------- MFMA GEMM
// C[N][COLS] = A[N][128] @ B[128][COLS]; C stored fp8 e4m3 (gather payload).
// Fused alpha epilogue on the f32 accumulators (alpha stays full precision).
template <int COLS, bool SRC_F32>
__global__ __launch_bounds__(256) void k_gemm_bf16(const void* __restrict__ Ap,
                                                   const unsigned short* __restrict__ Bt,
                                                   unsigned char* __restrict__ C,
                                                   const float* __restrict__ av_src,
                                                   const float* __restrict__ av_dst,
                                                   float* __restrict__ as_,
                                                   float* __restrict__ ad_,
                                                   int N) {
  constexpr int K = 128;
  constexpr int LDA = K + 8;
  __shared__ __align__(16) unsigned short As[64 * LDA];
  __shared__ __align__(16) unsigned short Bs[COLS * LDA];
  const int t = threadIdx.x;
  const int wave = t >> 6, lane = t & 63;
  const int row0 = blockIdx.x * 64;

#pragma unroll
  for (int i = 0; i < 4; ++i) {
    int c = t + 256 * i;
    int r = c >> 4, cq = c & 15;
    int4 v = make_int4(0, 0, 0, 0);
    if (row0 + r < N) {
      if constexpr (SRC_F32) {
        const float* Ar = (const float*)Ap + (size_t)(row0 + r) * K + cq * 8;
        float4 u = *reinterpret_cast<const float4*>(Ar);
        float4 w = *reinterpret_cast<const float4*>(Ar + 4);
        v.x = (int)f2b(u.x) | ((int)f2b(u.y) << 16);
        v.y = (int)f2b(u.z) | ((int)f2b(u.w) << 16);
        v.z = (int)f2b(w.x) | ((int)f2b(w.y) << 16);
        v.w = (int)f2b(w.z) | ((int)f2b(w.w) << 16);
      } else {
        v = *reinterpret_cast<const int4*>((const unsigned short*)Ap +
                                           (size_t)(row0 + r) * K + cq * 8);
      }
    }
    *reinterpret_cast<int4*>(&As[r * LDA + cq * 8]) = v;
  }
#pragma unroll
  for (int i = 0; i < COLS / 16; ++i) {
    int c = t + 256 * i;
    int r = c >> 4, cq = c & 15;
    *reinterpret_cast<int4*>(&Bs[r * LDA + cq * 8]) =
        *reinterpret_cast<const int4*>(Bt + (size_t)r * K + cq * 8);
  }
  __syncthreads();

  const int m15 = lane & 15;
  const int koff = (lane >> 4) * 8;
  const int arow = wave * 16 + m15;

  f32x4 acc[COLS / 16];
#pragma unroll
  for (int ct = 0; ct < COLS / 16; ++ct) acc[ct] = (f32x4){0.f, 0.f, 0.f, 0.f};

#pragma unroll
  for (int kk = 0; kk < K / 32; ++kk) {
    short8 af = *reinterpret_cast<const short8*>(&As[arow * LDA + kk * 32 + koff]);
#pragma unroll
    for (int ct = 0; ct < COLS / 16; ++ct) {
      short8 bf = *reinterpret_cast<const short8*>(&Bs[(ct * 16 + m15) * LDA + kk * 32 + koff]);
      acc[ct] = __builtin_amdgcn_mfma_f32_16x16x32_bf16(af, bf, acc[ct], 0, 0, 0);
    }
  }

  // C store (fp8 bytes)
#pragma unroll
  for (int ct = 0; ct < COLS / 16; ++ct) {
#pragma unroll
    for (int r = 0; r < 4; ++r) {
      int grow = row0 + wave * 16 + (lane >> 4) * 4 + r;
      if (grow < N)
        C[(size_t)grow * COLS + ct * 16 + m15] = f2f8(acc[ct][r]);
    }
  }

  // fused alpha epilogue (f32-accurate)
  {
    float ps[4] = {0.f, 0.f, 0.f, 0.f}, pd[4] = {0.f, 0.f, 0.f, 0.f};
#pragma unroll
    for (int ct = 0; ct < COLS / 16; ++ct) {
      float av = av_src[ct * 16 + m15];
      float bv = av_dst[ct * 16 + m15];
#pragma unroll
      for (int r = 0; r < 4; ++r) {
        ps[r] += acc[ct][r] * av;
        pd[r] += acc[ct][r] * bv;
      }
    }
#pragma unroll
    for (int o = 1; o < 16; o <<= 1) {
#pragma unroll
      for (int r = 0; r < 4; ++r) {
        ps[r] += __shfl_xor(ps[r], o);
        pd[r] += __shfl_xor(pd[r], o);
      }
    }
    if (m15 == 0) {
#pragma unroll
      for (int r = 0; r < 4; ++r) {
        int grow = row0 + wave * 16 + (lane >> 4) * 4 + r;
        if (grow < N) { as_[grow] = ps[r]; ad_[grow] = pd[r]; }
      }
    }
  }
}

// ---------------------------------------------------------------- aggregation
// One wave per dst node, single pass over fp8 h:
//   out = (sum_j exp(e_j) h[src_j]) / sum_j exp(e_j)  (+bias, opt ReLU)
// Lane loads uint2 (8 fp8) => wave covers GPI=64/(F/8) rows per load; DEPTH
// row-groups in flight (DEPTH*GPI = 32 edges ≈ mean degree).
template <int F, int DEPTH, bool RELU, bool OUT_BF16>
__global__ __launch_bounds__(256) void k_agg(const int* __restrict__ off,
                                             const int* __restrict__ csr,
                                             const float* __restrict__ as_,
                                             const float* __restrict__ ad_,
                                             const unsigned char* __restrict__ h,
                                             const float* __restrict__ bias,
                                             void* __restrict__ outp, int N) {
  constexpr int LPR = F / 8;      // lanes per row (16 or 8)
  constexpr int GPI = 64 / LPR;   // rows per load wave-wide (4 or 8)
  int wid = (blockIdx.x * blockDim.x + threadIdx.x) >> 6;
  int lane = threadIdx.x & 63;
  if (wid >= N) return;
  const int s0 = off[wid], s1 = off[wid + 1];
  const float adv = ad_[wid];
  const int g  = lane / LPR;
  const int fl = lane % LPR;
  const unsigned char* hb = h + (size_t)fl * 8;

  float acc[8] = {0.f, 0.f, 0.f, 0.f, 0.f, 0.f, 0.f, 0.f};
  float lsum = 0.f;

  for (int base = s0; base < s1; base += 64) {
    int i = base + lane;
    int sv = 0;
    float wexp = 0.f;
    if (i < s1) {
      sv = csr[i];
      float e = as_[sv] + adv;
      e = (e > 0.f) ? e : LEAKY_SLOPE * e;
      wexp = __expf(e);
      lsum += wexp;
    }
    const int jn = min(64, s1 - base);
    int jj = 0;
    for (; jj + DEPTH * GPI <= jn; jj += DEPTH * GPI) {
      int sj[DEPTH];
      float wv[DEPTH];
      uint2 u[DEPTH];
#pragma unroll
      for (int k = 0; k < DEPTH; ++k) {
        sj[k] = __shfl(sv, jj + g + k * GPI);
        wv[k] = __shfl(wexp, jj + g + k * GPI);
      }
#pragma unroll
      for (int k = 0; k < DEPTH; ++k)
        u[k] = *reinterpret_cast<const uint2*>(hb + (size_t)sj[k] * F);
#pragma unroll
      for (int k = 0; k < DEPTH; ++k)
        fma8f8(acc, u[k], wv[k]);
    }
    for (; jj < jn; jj += GPI) {
      int sj0 = __shfl(sv, jj + g);        // <= 63 always; zero-weight slack ok
      float w0 = __shfl(wexp, jj + g);
      uint2 u0 = *reinterpret_cast<const uint2*>(hb + (size_t)sj0 * F);
      fma8f8(acc, u0, w0);
    }
  }

  // denominator
  for (int o = 32; o; o >>= 1) lsum += __shfl_xor(lsum, o);
  const float inv_s = 1.f / (lsum + 1e-16f);

  // cross-group feature reduction
#pragma unroll
  for (int o = LPR; o < 64; o <<= 1) {
#pragma unroll
    for (int k = 0; k < 8; ++k) acc[k] += __shfl_xor(acc[k], o);
  }

  if (g == 0) {
    float ov[8];
#pragma unroll
    for (int k = 0; k < 8; ++k) {
      ov[k] = acc[k] * inv_s + bias[fl * 8 + k];
      if (RELU) ov[k] = fmaxf(ov[k], 0.f);
    }
    if constexpr (OUT_BF16) {
      int4 pk;
      pk.x = (int)f2b(ov[0]) | ((int)f2b(ov[1]) << 16);
      pk.y = (int)f2b(ov[2]) | ((int)f2b(ov[3]) << 16);
      pk.z = (int)f2b(ov[4]) | ((int)f2b(ov[5]) << 16);
      pk.w = (int)f2b(ov[6]) | ((int)f2b(ov[7]) << 16);
      *reinterpret_cast<int4*>((unsigned short*)outp + (size_t)wid * F + fl * 8) = pk;
    } else {
      float* op = (float*)outp + (size_t)wid * F + fl * 8;
      *reinterpret_cast<float4*>(op) = make_float4(ov[0], ov[1], ov[2], ov[3]);
      *reinterpret_cast<float4*>(op + 4) = make_float4(ov[4], ov[5], ov[6], ov[7]);
    }
  }
}

// ---------------------------------------------------------------- final mean
__global__ __launch_bounds__(256) void k_mean(const float* __restrict__ out2,
                                              float* __restrict__ d_out, int N) {
  int c = threadIdx.x & 63;
  int w = threadIdx.x >> 6;
  float acc = 0.f;
  for (int r = blockIdx.x * 4 + w; r < N; r += gridDim.x * 4)
    acc += out2[(size_t)r * 64 + c];
  atomicAdd(&d_out[c], acc * (1.0f / (float)N));
}

// ---------------------------------------------------------------- launch
extern "C" void kernel_launch(void* const* d_in, const int* in_sizes, int n_in,
                              void* d_out, int out_size, void* d_ws, size_t ws_size,
                              hipStream_t stream) {
  (void)n_in; (void)out_size; (void)ws_size;
  const float* x      = (const float*)d_in[0];
  const int*   edges  = (const int*)d_in[1];
  const float* W1     = (const float*)d_in[2];
  const float* a1_src = (const float*)d_in[3];
  const float* a1_dst = (const float*)d_in[4];
  const float* b1     = (const float*)d_in[5];
  const float* W2     = (const float*)d_in[6];
  const float* a2_src = (const float*)d_in[7];
  const float* a2_dst = (const float*)d_in[8];
  const float* b2     = (const float*)d_in[9];
  float* out = (float*)d_out;

  const int N = in_sizes[0] / 128;     // 100000
  const int E = in_sizes[1] / 2;       // 3200000
  const int ET = E + N;
  const int NB = (N + 255) >> 8;       // 391 buckets of 256 nodes

  const int* e_src = edges;
  const int* e_dst = edges + E;

  char* ws = (char*)d_ws;
  size_t o = 0;
  auto alloc = [&](size_t bytes) {
    size_t p = o;
    o += (bytes + 511) & ~(size_t)511;
    return p;
  };
  unsigned char*  h1f = (unsigned char*)(ws + alloc((size_t)N * 128));
  unsigned short* g1b = (unsigned short*)(ws + alloc((size_t)N * 128 * 2));
  unsigned char*  h2f = (unsigned char*)(ws + alloc((size_t)N * 64));
  float* out2   = (float*)(ws + alloc((size_t)N * 64 * 4));
  float* as1    = (float*)(ws + alloc((size_t)N * 4));
  float* ad1    = (float*)(ws + alloc((size_t)N * 4));
  float* as2    = (float*)(ws + alloc((size_t)N * 4));
  float* ad2    = (float*)(ws + alloc((size_t)N * 4));
  int*   off    = (int*)(ws + alloc((size_t)(N + 1) * 4));
  int*   gcount = (int*)(ws + alloc((size_t)(NB + 1) * 4));
  int*   gbase  = (int*)(ws + alloc((size_t)(NB + 1) * 4));
  int*   gcursor= (int*)(ws + alloc((size_t)(NB + 1) * 4));
  unsigned int* staging = (unsigned int*)(ws + alloc((size_t)ET * 4));
  int*   csr    = (int*)(ws + alloc((size_t)ET * 4));
  unsigned short* W1t = (unsigned short*)(ws + alloc((size_t)128 * 128 * 2));
  unsigned short* W2t = (unsigned short*)(ws + alloc((size_t)64 * 128 * 2));

  // --- CSR build: bucketed counting sort ---
  hipMemsetAsync(gcount, 0, (size_t)NB * 4, stream);
  k_bhist<<<512, 256, 0, stream>>>(e_dst, gcount, E, N, NB);
  k_bscan<<<1, 512, 0, stream>>>(gcount, gbase, gcursor, NB, ET, off + N);
  constexpr int CHUNK = 8192;
  k_binpass<CHUNK><<<(ET + CHUNK - 1) / CHUNK, 256, 0, stream>>>(
      e_src, e_dst, gcursor, staging, E, N, NB);
  k_csrbuild<<<NB, 256, 0, stream>>>(gbase, staging, off, csr, N);

  // --- weights ---
  k_prep_w<<<1, 256, 0, stream>>>(W1, W2, W1t, W2t);

  const int gemm_grid = (N + 63) / 64;
  const int node_wave_grid = (N + 3) / 4;

  // --- layer 1 (GEMM + fused alpha, then single-pass fp8-payload agg) ---
  k_gemm_bf16<128, true><<<gemm_grid, 256, 0, stream>>>(
      x, W1t, h1f, a1_src, a1_dst, as1, ad1, N);
  k_agg<128, 8, true, true><<<node_wave_grid, 256, 0, stream>>>(
      off, csr, as1, ad1, h1f, b1, (void*)g1b, N);

  // --- layer 2 ---
  k_gemm_bf16<64, false><<<gemm_grid, 256, 0, stream>>>(
      g1b, W2t, h2f, a2_src, a2_dst, as2, ad2, N);
  k_agg<64, 4, false, false><<<node_wave_grid, 256, 0, stream>>>(
      off, csr, as2, ad2, h2f, b2, (void*)out2, N);

  // --- mean ---
  hipMemsetAsync(out, 0, 64 * sizeof(float), stream);
  k_mean<<<256, 256, 0, stream>>>(out2, out, N);
}